// Round 1
// baseline (12094.209 us; speedup 1.0000x reference)
//
#include <hip/hip_runtime.h>
#include <hip/hip_fp16.h>

#define C_ 32
#define I_ 32
#define W_ 32
#define R_ 36
#define D_ 1024
#define KC 128
#define EPS_ 1e-8f
#define LAMBDA_ 9.0f
#define MARGIN_ 0.2f

__device__ __forceinline__ float4 loadHalf4(const __half* p) {
    const __half2 a = *(const __half2*)(p);
    const __half2 b = *(const __half2*)(p + 2);
    float2 fa = __half22float2(a), fb = __half22float2(b);
    return make_float4(fa.x, fa.y, fb.x, fb.y);
}

// One WG per (c,i). Computes attn -> leaky_relu -> masked row-norm ->
// softmax over r -> wc (written fp16) -> cos -> score += .
__global__ __launch_bounds__(256) void attn_kernel(
    const float* __restrict__ img,      // (I,R,D)
    const float* __restrict__ cap,      // (C,W,D)
    const __half* __restrict__ qcur,    // (C,I,W,D) fp16, or unused if iter0
    const int* __restrict__ lens,
    __half* __restrict__ wc_out,        // (C,I,W,D) fp16
    float* __restrict__ score,          // (C,I)
    const int iter0)
{
    __shared__ float sImg[R_][KC + 4];   // odd-granule pad
    __shared__ float sQ[W_][KC + 4];
    __shared__ float sAttn[R_][W_ + 1];
    __shared__ float sSmT[W_][40];       // transposed softmax, r padded to 40
    __shared__ float sNrm[R_];
    __shared__ float sRed[4];

    const int ci = blockIdx.x;
    const int c  = ci >> 5;
    const int i  = ci & 31;
    const int len = lens[c];
    const int tid = threadIdx.x;
    const int lane = tid & 63;
    const int wv = tid >> 6;
    const int aw = tid & 31;   // phase-A w
    const int rg = tid >> 5;   // phase-A r-group 0..7

    const float* imgI = img + (size_t)i * (R_ * D_);
    const float* capC = cap + (size_t)c * (W_ * D_);
    const __half* qC = iter0 ? (const __half*)0 : (qcur + (size_t)ci * (W_ * D_));

    float acc[5] = {0.f, 0.f, 0.f, 0.f, 0.f};

    // ---------------- Phase A: attn[r][w] = img[i,r,:] . q[c,i,w,:]
    for (int k0 = 0; k0 < D_; k0 += KC) {
        for (int idx = tid; idx < R_ * (KC / 4); idx += 256) {
            int r = idx >> 5, kq = idx & 31;
            float4 v = *(const float4*)(imgI + r * D_ + k0 + kq * 4);
            *(float4*)&sImg[r][kq * 4] = v;
        }
        if (iter0) {
            for (int idx = tid; idx < W_ * (KC / 4); idx += 256) {
                int w = idx >> 5, kq = idx & 31;
                float4 v = *(const float4*)(capC + w * D_ + k0 + kq * 4);
                *(float4*)&sQ[w][kq * 4] = v;
            }
        } else {
            for (int idx = tid; idx < W_ * (KC / 4); idx += 256) {
                int w = idx >> 5, kq = idx & 31;
                float4 v = loadHalf4(qC + w * D_ + k0 + kq * 4);
                *(float4*)&sQ[w][kq * 4] = v;
            }
        }
        __syncthreads();
        if (aw < len) {
            for (int kk = 0; kk < KC; kk += 4) {
                const float4 q4 = *(const float4*)&sQ[aw][kk];
                #pragma unroll
                for (int j = 0; j < 5; j++) {
                    const int r = rg + j * 8;
                    if (r < R_) {
                        const float4 a4 = *(const float4*)&sImg[r][kk];
                        acc[j] += a4.x * q4.x + a4.y * q4.y + a4.z * q4.z + a4.w * q4.w;
                    }
                }
            }
        }
        __syncthreads();
    }

    // leaky_relu, stash to LDS
    if (aw < len) {
        #pragma unroll
        for (int j = 0; j < 5; j++) {
            const int r = rg + j * 8;
            if (r < R_) {
                float v = acc[j];
                sAttn[r][aw] = (v >= 0.f) ? v : 0.1f * v;
            }
        }
    }
    __syncthreads();

    // masked row norms over w<len
    if (tid < R_) {
        float s = 0.f;
        for (int w = 0; w < len; w++) { float v = sAttn[tid][w]; s += v * v; }
        sNrm[tid] = sqrtf(s) + EPS_;
    }
    __syncthreads();

    // softmax over r per valid w; write transposed
    if (tid < len) {
        float vals[R_];
        float m = -1e30f;
        #pragma unroll
        for (int r = 0; r < R_; r++) {
            float v = (sAttn[r][tid] / sNrm[r]) * LAMBDA_;
            vals[r] = v;
            m = fmaxf(m, v);
        }
        float sum = 0.f;
        #pragma unroll
        for (int r = 0; r < R_; r++) { float e = __expf(vals[r] - m); sum += e; vals[r] = e; }
        const float inv = 1.0f / sum;
        #pragma unroll
        for (int r = 0; r < R_; r++) sSmT[tid][r] = vals[r] * inv;
    }
    __syncthreads();

    // ---------------- Phase B: wc = sm^T . img ; cos ; score
    float w12[8], w22[8], w11[8];
    #pragma unroll
    for (int t = 0; t < 8; t++) { w12[t] = 0.f; w22[t] = 0.f; w11[t] = 0.f; }
    __half* wcC = wc_out + (size_t)ci * (W_ * D_);

    for (int k0 = 0; k0 < D_; k0 += KC) {
        for (int idx = tid; idx < R_ * (KC / 4); idx += 256) {
            int r = idx >> 5, kq = idx & 31;
            float4 v = *(const float4*)(imgI + r * D_ + k0 + kq * 4);
            *(float4*)&sImg[r][kq * 4] = v;
        }
        __syncthreads();
        const int dl = lane * 2;
        #pragma unroll
        for (int t = 0; t < 8; t++) {
            const int w = wv + t * 4;
            if (w < len) {
                float ax = 0.f, ay = 0.f;
                #pragma unroll
                for (int r4 = 0; r4 < 9; r4++) {
                    const float4 sm4 = *(const float4*)&sSmT[w][r4 * 4];
                    float2 a0 = *(const float2*)&sImg[r4 * 4 + 0][dl];
                    ax += sm4.x * a0.x; ay += sm4.x * a0.y;
                    float2 a1 = *(const float2*)&sImg[r4 * 4 + 1][dl];
                    ax += sm4.y * a1.x; ay += sm4.y * a1.y;
                    float2 a2 = *(const float2*)&sImg[r4 * 4 + 2][dl];
                    ax += sm4.z * a2.x; ay += sm4.z * a2.y;
                    float2 a3 = *(const float2*)&sImg[r4 * 4 + 3][dl];
                    ax += sm4.w * a3.x; ay += sm4.w * a3.y;
                }
                float2 acc2 = make_float2(ax, ay);
                *(__half2*)(wcC + w * D_ + k0 + dl) = __float22half2_rn(acc2);
                const float2 cp = *(const float2*)(capC + w * D_ + k0 + dl);
                w12[t] += cp.x * ax + cp.y * ay;
                w22[t] += ax * ax + ay * ay;
                w11[t] += cp.x * cp.x + cp.y * cp.y;
            }
        }
        __syncthreads();
    }

    float mysum = 0.f;
    #pragma unroll
    for (int t = 0; t < 8; t++) {
        float a = w12[t], b = w22[t], d = w11[t];
        for (int off = 32; off > 0; off >>= 1) {
            a += __shfl_down(a, off);
            b += __shfl_down(b, off);
            d += __shfl_down(d, off);
        }
        const int w = wv + t * 4;
        if (lane == 0 && w < len) {
            const float denom = fmaxf(sqrtf(d) * sqrtf(b), EPS_);
            mysum += a / denom;
        }
    }
    if (lane == 0) sRed[wv] = mysum;
    __syncthreads();
    if (tid == 0) {
        const float tot = sRed[0] + sRed[1] + sRed[2] + sRed[3];
        score[ci] += tot / (float)len;
    }
}

// Gating MLP: h = tanh(cat@Wl^T + bl), g = sigmoid(cat@Wg^T + bg),
// qnext = q*g + h*(1-g). cat = [q, wc]. M-tile = 128 rows (4 i of one c),
// N-tile = 128 j (both mats). Only rows w<len computed.
__global__ __launch_bounds__(1024) void mlp_kernel(
    const float* __restrict__ cap,
    const __half* __restrict__ qcur,
    const __half* __restrict__ wc,
    const float* __restrict__ w_lin, const float* __restrict__ b_lin,
    const float* __restrict__ w_gate, const float* __restrict__ b_gate,
    __half* __restrict__ qnext,
    const int* __restrict__ lens,
    const int iter0)
{
    __shared__ float sA[128][36];
    __shared__ float sBh[128][36];
    __shared__ float sBg[128][36];

    const int bx = blockIdx.x;          // 0..255 : c * i-quad
    const int jt = blockIdx.y;          // 0..7
    const int c  = bx >> 3;
    const int i0 = (bx & 7) * 4;
    const int len = lens[c];
    const int tid = threadIdx.x;
    const int lane = tid & 63;
    const int wv = tid >> 6;            // 0..15
    const int isub = wv >> 2;           // 0..3
    const int wg = wv & 3;              // 0..3
    const int ci = c * 32 + i0 + isub;

    // load mapping
    const int lrow = tid >> 3;          // 0..127
    const int lkq  = tid & 7;           // 0..7
    const int li   = lrow >> 5;
    const int lw   = lrow & 31;
    const int ci_l = c * 32 + i0 + li;
    const float*  caprow = cap + ((size_t)c * 32 + lw) * D_ + lkq * 4;
    const __half* qrow   = iter0 ? (const __half*)0 : qcur + ((size_t)ci_l * 32 + lw) * D_ + lkq * 4;
    const __half* wcrow  = wc + ((size_t)ci_l * 32 + lw) * D_ + lkq * 4;
    const float*  bhrow  = w_lin  + (size_t)(jt * 128 + lrow) * 2048 + lkq * 4;
    const float*  bgrow  = w_gate + (size_t)(jt * 128 + lrow) * 2048 + lkq * 4;

    float acch0[8], acch1[8], accg0[8], accg1[8];
    #pragma unroll
    for (int t = 0; t < 8; t++) { acch0[t] = 0.f; acch1[t] = 0.f; accg0[t] = 0.f; accg1[t] = 0.f; }

    // prefetch chunk 0
    float4 nA, nBh, nBg;
    {
        if (iter0) nA = *(const float4*)(caprow);
        else       nA = loadHalf4(qrow);
        nBh = *(const float4*)(bhrow);
        nBg = *(const float4*)(bgrow);
    }

    for (int kc = 0; kc < 64; kc++) {
        __syncthreads();
        *(float4*)&sA [lrow][lkq * 4] = nA;
        *(float4*)&sBh[lrow][lkq * 4] = nBh;
        *(float4*)&sBg[lrow][lkq * 4] = nBg;
        if (kc < 63) {
            const int k0 = (kc + 1) * 32;
            if (k0 < 1024) {
                if (iter0) nA = *(const float4*)(caprow + k0);
                else       nA = loadHalf4(qrow + k0);
            } else {
                nA = loadHalf4(wcrow + (k0 - 1024));
            }
            nBh = *(const float4*)(bhrow + k0);
            nBg = *(const float4*)(bgrow + k0);
        }
        __syncthreads();

        #pragma unroll
        for (int k4 = 0; k4 < 8; k4++) {
            const float4 bh0 = *(const float4*)&sBh[lane][k4 * 4];
            const float4 bh1 = *(const float4*)&sBh[lane + 64][k4 * 4];
            const float4 bg0 = *(const float4*)&sBg[lane][k4 * 4];
            const float4 bg1 = *(const float4*)&sBg[lane + 64][k4 * 4];
            #pragma unroll
            for (int t = 0; t < 8; t++) {
                const int w = wg + t * 4;
                if (w < len) {
                    const float4 a4 = *(const float4*)&sA[(isub << 5) + w][k4 * 4];
                    acch0[t] += a4.x * bh0.x + a4.y * bh0.y + a4.z * bh0.z + a4.w * bh0.w;
                    acch1[t] += a4.x * bh1.x + a4.y * bh1.y + a4.z * bh1.z + a4.w * bh1.w;
                    accg0[t] += a4.x * bg0.x + a4.y * bg0.y + a4.z * bg0.z + a4.w * bg0.w;
                    accg1[t] += a4.x * bg1.x + a4.y * bg1.y + a4.z * bg1.z + a4.w * bg1.w;
                }
            }
        }
    }

    // epilogue: activations + gated q update
    #pragma unroll
    for (int t = 0; t < 8; t++) {
        const int w = wg + t * 4;
        if (w < len) {
            #pragma unroll
            for (int jj = 0; jj < 2; jj++) {
                const int jg = jt * 128 + lane + jj * 64;
                const float hp = (jj ? acch1[t] : acch0[t]) + b_lin[jg];
                const float gp = (jj ? accg1[t] : accg0[t]) + b_gate[jg];
                const float g = 1.f / (1.f + __expf(-gp));
                const float h = tanhf(hp);
                const size_t off = ((size_t)ci * 32 + w) * D_ + jg;
                float qold;
                if (iter0) qold = cap[((size_t)c * 32 + w) * D_ + jg];
                else       qold = __half2float(qcur[off]);
                qnext[off] = __float2half(qold * g + h * (1.f - g));
            }
        }
    }
}

__global__ __launch_bounds__(64) void loss_kernel(const float* __restrict__ score,
                                                  float* __restrict__ out)
{
    __shared__ float s[32][33];
    __shared__ float diag[32];
    const int tid = threadIdx.x;
    for (int idx = tid; idx < 1024; idx += 64) s[idx >> 5][idx & 31] = score[idx];
    __syncthreads();
    if (tid < 32) diag[tid] = s[tid][tid];
    __syncthreads();
    float total = 0.f;
    if (tid < 32) {
        float m1 = 0.f, m2 = 0.f;
        for (int k = 0; k < 32; k++) {
            if (k != tid) {
                m1 = fmaxf(m1, fmaxf(0.f, MARGIN_ + s[tid][k] - diag[tid]));
                m2 = fmaxf(m2, fmaxf(0.f, MARGIN_ + s[k][tid] - diag[tid]));
            }
        }
        total = m1 + m2;
    }
    for (int off = 32; off > 0; off >>= 1) total += __shfl_down(total, off);
    if (tid == 0) out[0] = total;
}

extern "C" void kernel_launch(void* const* d_in, const int* in_sizes, int n_in,
                              void* d_out, int out_size, void* d_ws, size_t ws_size,
                              hipStream_t stream) {
    const float* img    = (const float*)d_in[0];
    const float* cap    = (const float*)d_in[1];
    const int*   lens   = (const int*)d_in[2];
    const float* w_lin  = (const float*)d_in[3];
    const float* b_lin  = (const float*)d_in[4];
    const float* w_gate = (const float*)d_in[5];
    const float* b_gate = (const float*)d_in[6];
    float* out = (float*)d_out;

    char* ws = (char*)d_ws;
    const size_t QSZ = (size_t)C_ * I_ * W_ * D_;   // elements
    __half* qA  = (__half*)(ws);
    __half* qB  = (__half*)(ws + QSZ * 2);
    __half* wcb = (__half*)(ws + QSZ * 4);
    float* score = (float*)(ws + QSZ * 6);

    hipMemsetAsync(score, 0, C_ * I_ * sizeof(float), stream);

    // iter 0 (q = cap broadcast, read directly)
    attn_kernel<<<dim3(C_ * I_), dim3(256), 0, stream>>>(img, cap, (const __half*)0, lens, wcb, score, 1);
    mlp_kernel<<<dim3(256, 8), dim3(1024), 0, stream>>>(cap, (const __half*)0, wcb, w_lin, b_lin, w_gate, b_gate, qA, lens, 1);
    // iter 1
    attn_kernel<<<dim3(C_ * I_), dim3(256), 0, stream>>>(img, cap, qA, lens, wcb, score, 0);
    mlp_kernel<<<dim3(256, 8), dim3(1024), 0, stream>>>(cap, qA, wcb, w_lin, b_lin, w_gate, b_gate, qB, lens, 0);
    // iter 2 (final q update is dead code -> no MLP)
    attn_kernel<<<dim3(C_ * I_), dim3(256), 0, stream>>>(img, cap, qB, lens, wcb, score, 0);

    loss_kernel<<<dim3(1), dim3(64), 0, stream>>>(score, out);
}

// Round 2
// 1414.724 us; speedup vs baseline: 8.5488x; 8.5488x over previous
//
#include <hip/hip_runtime.h>
#include <hip/hip_fp16.h>

#define C_ 32
#define I_ 32
#define W_ 32
#define R_ 36
#define D_ 1024
#define KC 128
#define EPS_ 1e-8f
#define LAMBDA_ 9.0f
#define MARGIN_ 0.2f

typedef _Float16 f16;
typedef f16 half8 __attribute__((ext_vector_type(8)));
typedef f16 f16x4 __attribute__((ext_vector_type(4)));
typedef float f32x4 __attribute__((ext_vector_type(4)));

__device__ __forceinline__ float4 loadHalf4(const __half* p) {
    const __half2 a = *(const __half2*)(p);
    const __half2 b = *(const __half2*)(p + 2);
    float2 fa = __half22float2(a), fb = __half22float2(b);
    return make_float4(fa.x, fa.y, fb.x, fb.y);
}

__device__ __forceinline__ void gload16(const void* g, void* l) {
    __builtin_amdgcn_global_load_lds((const __attribute__((address_space(1))) void*)g,
                                     (__attribute__((address_space(3))) void*)l, 16, 0, 0);
}

// fp32 -> fp16 conversion of cap, w_lin, w_gate (once per launch)
__global__ __launch_bounds__(256) void convert_kernel(
    const float* __restrict__ cap, const float* __restrict__ wl, const float* __restrict__ wg,
    f16* __restrict__ capH, f16* __restrict__ wlH, f16* __restrict__ wgH)
{
    const int t = blockIdx.x * 256 + threadIdx.x;   // one float4 each
    const float* src; f16* dst; int idx;
    if (t < 262144)       { src = cap; dst = capH; idx = t; }
    else if (t < 786432)  { src = wl;  dst = wlH;  idx = t - 262144; }
    else                  { src = wg;  dst = wgH;  idx = t - 786432; }
    float4 v = ((const float4*)src)[idx];
    f16x4 o; o[0] = (f16)v.x; o[1] = (f16)v.y; o[2] = (f16)v.z; o[3] = (f16)v.w;
    *(f16x4*)(dst + (size_t)idx * 4) = o;
}

// One WG per (c,i). attn -> leaky_relu -> masked row-norm -> softmax over r
// -> wc (fp16, layout (c,w,i,d)) -> cos -> score += .
__global__ __launch_bounds__(256) void attn_kernel(
    const float* __restrict__ img,      // (I,R,D)
    const float* __restrict__ cap,      // (C,W,D)
    const __half* __restrict__ qcur,    // (C,W,I,D) fp16, unused if iter0
    const int* __restrict__ lens,
    __half* __restrict__ wc_out,        // (C,W,I,D) fp16
    float* __restrict__ score,          // (C,I)
    const int iter0)
{
    __shared__ float sImg[R_][KC + 4];
    __shared__ float sQ[W_][KC + 4];
    __shared__ float sAttn[R_][W_ + 1];
    __shared__ float sSmT[W_][40];
    __shared__ float sNrm[R_];
    __shared__ float sRed[4];

    const int ci = blockIdx.x;
    const int c  = ci >> 5;
    const int i  = ci & 31;
    const int len = lens[c];
    const int tid = threadIdx.x;
    const int lane = tid & 63;
    const int wv = tid >> 6;
    const int aw = tid & 31;
    const int rg = tid >> 5;

    const float* imgI = img + (size_t)i * (R_ * D_);
    const float* capC = cap + (size_t)c * (W_ * D_);
    // (c,w,i,d): base for this (c,i), stride 32*D_ between w
    const __half* qB = iter0 ? (const __half*)0 : (qcur + ((size_t)c * 1024 + i) * D_);

    float acc[5] = {0.f, 0.f, 0.f, 0.f, 0.f};

    for (int k0 = 0; k0 < D_; k0 += KC) {
        for (int idx = tid; idx < R_ * (KC / 4); idx += 256) {
            int r = idx >> 5, kq = idx & 31;
            float4 v = *(const float4*)(imgI + r * D_ + k0 + kq * 4);
            *(float4*)&sImg[r][kq * 4] = v;
        }
        if (iter0) {
            for (int idx = tid; idx < W_ * (KC / 4); idx += 256) {
                int w = idx >> 5, kq = idx & 31;
                float4 v = *(const float4*)(capC + w * D_ + k0 + kq * 4);
                *(float4*)&sQ[w][kq * 4] = v;
            }
        } else {
            for (int idx = tid; idx < W_ * (KC / 4); idx += 256) {
                int w = idx >> 5, kq = idx & 31;
                float4 v = loadHalf4(qB + (size_t)w * (32 * D_) + k0 + kq * 4);
                *(float4*)&sQ[w][kq * 4] = v;
            }
        }
        __syncthreads();
        if (aw < len) {
            for (int kk = 0; kk < KC; kk += 4) {
                const float4 q4 = *(const float4*)&sQ[aw][kk];
                #pragma unroll
                for (int j = 0; j < 5; j++) {
                    const int r = rg + j * 8;
                    if (r < R_) {
                        const float4 a4 = *(const float4*)&sImg[r][kk];
                        acc[j] += a4.x * q4.x + a4.y * q4.y + a4.z * q4.z + a4.w * q4.w;
                    }
                }
            }
        }
        __syncthreads();
    }

    if (aw < len) {
        #pragma unroll
        for (int j = 0; j < 5; j++) {
            const int r = rg + j * 8;
            if (r < R_) {
                float v = acc[j];
                sAttn[r][aw] = (v >= 0.f) ? v : 0.1f * v;
            }
        }
    }
    __syncthreads();

    if (tid < R_) {
        float s = 0.f;
        for (int w = 0; w < len; w++) { float v = sAttn[tid][w]; s += v * v; }
        sNrm[tid] = sqrtf(s) + EPS_;
    }
    __syncthreads();

    if (tid < len) {
        float vals[R_];
        float m = -1e30f;
        #pragma unroll
        for (int r = 0; r < R_; r++) {
            float v = (sAttn[r][tid] / sNrm[r]) * LAMBDA_;
            vals[r] = v;
            m = fmaxf(m, v);
        }
        float sum = 0.f;
        #pragma unroll
        for (int r = 0; r < R_; r++) { float e = __expf(vals[r] - m); sum += e; vals[r] = e; }
        const float inv = 1.0f / sum;
        #pragma unroll
        for (int r = 0; r < R_; r++) sSmT[tid][r] = vals[r] * inv;
    }
    __syncthreads();

    float w12[8], w22[8], w11[8];
    #pragma unroll
    for (int t = 0; t < 8; t++) { w12[t] = 0.f; w22[t] = 0.f; w11[t] = 0.f; }
    __half* wcB = wc_out + ((size_t)c * 1024 + i) * D_;

    for (int k0 = 0; k0 < D_; k0 += KC) {
        for (int idx = tid; idx < R_ * (KC / 4); idx += 256) {
            int r = idx >> 5, kq = idx & 31;
            float4 v = *(const float4*)(imgI + r * D_ + k0 + kq * 4);
            *(float4*)&sImg[r][kq * 4] = v;
        }
        __syncthreads();
        const int dl = lane * 2;
        #pragma unroll
        for (int t = 0; t < 8; t++) {
            const int w = wv + t * 4;
            if (w < len) {
                float ax = 0.f, ay = 0.f;
                #pragma unroll
                for (int r4 = 0; r4 < 9; r4++) {
                    const float4 sm4 = *(const float4*)&sSmT[w][r4 * 4];
                    float2 a0 = *(const float2*)&sImg[r4 * 4 + 0][dl];
                    ax += sm4.x * a0.x; ay += sm4.x * a0.y;
                    float2 a1 = *(const float2*)&sImg[r4 * 4 + 1][dl];
                    ax += sm4.y * a1.x; ay += sm4.y * a1.y;
                    float2 a2 = *(const float2*)&sImg[r4 * 4 + 2][dl];
                    ax += sm4.z * a2.x; ay += sm4.z * a2.y;
                    float2 a3 = *(const float2*)&sImg[r4 * 4 + 3][dl];
                    ax += sm4.w * a3.x; ay += sm4.w * a3.y;
                }
                float2 acc2 = make_float2(ax, ay);
                *(__half2*)(wcB + (size_t)w * (32 * D_) + k0 + dl) = __float22half2_rn(acc2);
                const float2 cp = *(const float2*)(capC + w * D_ + k0 + dl);
                w12[t] += cp.x * ax + cp.y * ay;
                w22[t] += ax * ax + ay * ay;
                w11[t] += cp.x * cp.x + cp.y * cp.y;
            }
        }
        __syncthreads();
    }

    float mysum = 0.f;
    #pragma unroll
    for (int t = 0; t < 8; t++) {
        float a = w12[t], b = w22[t], d = w11[t];
        for (int off = 32; off > 0; off >>= 1) {
            a += __shfl_down(a, off);
            b += __shfl_down(b, off);
            d += __shfl_down(d, off);
        }
        const int w = wv + t * 4;
        if (lane == 0 && w < len) {
            const float denom = fmaxf(sqrtf(d) * sqrtf(b), EPS_);
            mysum += a / denom;
        }
    }
    if (lane == 0) sRed[wv] = mysum;
    __syncthreads();
    if (tid == 0) {
        const float tot = sRed[0] + sRed[1] + sRed[2] + sRed[3];
        score[ci] += tot / (float)len;
    }
}

// MFMA fp16 gating MLP.  A = [q | wc] (M=32768 rows in (c,w,i) order, K=2048),
// B = [w_lin ; w_gate] rows (B^T layout, row-major N x K).
// BM=128, BN=128 (64 j-cols x {lin,gate}), BK=64, 4 waves x (64x64).
// grid.x = 256 (c * 8 m-tiles), grid.y = 16 (j-tiles of 64).
__global__ __launch_bounds__(256) void mlp_kernel(
    const float* __restrict__ cap,      // fp32, exact qold for iter0
    const f16* __restrict__ capH,
    const f16* __restrict__ qcur,       // (C,W,I,D)
    const f16* __restrict__ wcb,        // (C,W,I,D)
    const f16* __restrict__ wlinH, const f16* __restrict__ wgateH,
    const float* __restrict__ b_lin, const float* __restrict__ b_gate,
    f16* __restrict__ qnext,            // (C,W,I,D)
    const int* __restrict__ lens,
    const int iter0)
{
    const int bx = blockIdx.x;
    const int c  = bx >> 3;
    const int mt = bx & 7;
    const int len = lens[c];
    if (mt * 4 >= len) return;          // whole tile masked out (uniform)
    const int jt = blockIdx.y;          // 0..15
    const int m0 = c * 1024 + mt * 128;

    __shared__ char sMem[32768];        // A: [0,16K), B: [16K,32K)

    const int tid = threadIdx.x;
    const int lane = tid & 63;
    const int wv = tid >> 6;            // 0..3
    const int wm = wv >> 1;             // 0..1
    const int wn = wv & 1;              // 0..1
    const int rsub = lane >> 3;         // 0..7
    const int ch = lane & 7;            // 16B chunk 0..7

    // per-thread staging sources (4 rows each for A and B)
    const f16* a1p[4]; const f16* a2p[4]; const f16* bp[4];
    char* ldsA[4]; char* ldsB[4];
    #pragma unroll
    for (int t = 0; t < 4; t++) {
        const int row = wv * 32 + t * 8 + rsub;
        const int m = m0 + row;
        const int sw = ((ch ^ (row & 7)) << 3);     // swizzled chunk offset (elems)
        a1p[t] = (iter0 ? (capH + ((size_t)(m >> 5) << 10)) : (qcur + ((size_t)m << 10))) + sw;
        a2p[t] = wcb + ((size_t)m << 10) + sw;
        const int n = row;                           // B lds row
        const f16* wrow = (n < 64) ? (wlinH + ((size_t)(jt * 64 + n) << 11))
                                   : (wgateH + ((size_t)(jt * 64 + n - 64) << 11));
        bp[t] = wrow + ((ch ^ (n & 7)) << 3);
        ldsA[t] = sMem + wv * 4096 + t * 1024;
        ldsB[t] = sMem + 16384 + wv * 4096 + t * 1024;
    }

    f32x4 acc[4][4];
    #pragma unroll
    for (int a = 0; a < 4; a++)
        #pragma unroll
        for (int b = 0; b < 4; b++)
            acc[a][b] = (f32x4){0.f, 0.f, 0.f, 0.f};

    for (int ks = 0; ks < 32; ks++) {
        const int kk = ks * 64;
        // stage A then B (16B per lane per call, linear LDS dest)
        if (kk < 1024) {
            #pragma unroll
            for (int t = 0; t < 4; t++) gload16(a1p[t] + kk, ldsA[t]);
        } else {
            #pragma unroll
            for (int t = 0; t < 4; t++) gload16(a2p[t] + (kk - 1024), ldsA[t]);
        }
        #pragma unroll
        for (int t = 0; t < 4; t++) gload16(bp[t] + kk, ldsB[t]);
        __syncthreads();

        #pragma unroll
        for (int ksub = 0; ksub < 2; ksub++) {
            const int kch = ksub * 4 + (lane >> 4);  // 16B chunk in row
            half8 af[4], bf[4];
            #pragma unroll
            for (int tm = 0; tm < 4; tm++) {
                const int row = wm * 64 + tm * 16 + (lane & 15);
                af[tm] = *(const half8*)(sMem + row * 128 + ((kch ^ (row & 7)) << 4));
            }
            #pragma unroll
            for (int tn = 0; tn < 4; tn++) {
                const int n = ((tn >> 1) << 6) + wn * 32 + ((tn & 1) << 4) + (lane & 15);
                bf[tn] = *(const half8*)(sMem + 16384 + n * 128 + ((kch ^ (n & 7)) << 4));
            }
            #pragma unroll
            for (int tm = 0; tm < 4; tm++)
                #pragma unroll
                for (int tn = 0; tn < 4; tn++)
                    acc[tm][tn] = __builtin_amdgcn_mfma_f32_16x16x32_f16(af[tm], bf[tn], acc[tm][tn], 0, 0, 0);
        }
        __syncthreads();
    }

    // epilogue: h = tanh(.+bl), g = sigmoid(.+bg), qnext = qold*g + h*(1-g)
    const int j0 = jt * 64 + wn * 32 + (lane & 15);
    const float bl0 = b_lin[j0],  bl1 = b_lin[j0 + 16];
    const float bg0 = b_gate[j0], bg1 = b_gate[j0 + 16];
    #pragma unroll
    for (int tm = 0; tm < 4; tm++) {
        #pragma unroll
        for (int tp = 0; tp < 2; tp++) {
            const f32x4 ha = acc[tm][tp];
            const f32x4 ga = acc[tm][tp + 2];
            const int j = j0 + tp * 16;
            const float bl = tp ? bl1 : bl0;
            const float bg = tp ? bg1 : bg0;
            #pragma unroll
            for (int r = 0; r < 4; r++) {
                const int m = m0 + wm * 64 + tm * 16 + (lane >> 4) * 4 + r;
                const int w = (m >> 5) & 31;
                if (w < len) {
                    const float hp = ha[r] + bl;
                    const float gp = ga[r] + bg;
                    const float g = 1.f / (1.f + __expf(-gp));
                    const float h = tanhf(hp);
                    const float qold = iter0 ? cap[((size_t)(m >> 5) << 10) + j]
                                             : (float)qcur[((size_t)m << 10) + j];
                    qnext[((size_t)m << 10) + j] = (f16)(qold * g + h * (1.f - g));
                }
            }
        }
    }
}

__global__ __launch_bounds__(64) void loss_kernel(const float* __restrict__ score,
                                                  float* __restrict__ out)
{
    __shared__ float s[32][33];
    __shared__ float diag[32];
    const int tid = threadIdx.x;
    for (int idx = tid; idx < 1024; idx += 64) s[idx >> 5][idx & 31] = score[idx];
    __syncthreads();
    if (tid < 32) diag[tid] = s[tid][tid];
    __syncthreads();
    float total = 0.f;
    if (tid < 32) {
        float m1 = 0.f, m2 = 0.f;
        for (int k = 0; k < 32; k++) {
            if (k != tid) {
                m1 = fmaxf(m1, fmaxf(0.f, MARGIN_ + s[tid][k] - diag[tid]));
                m2 = fmaxf(m2, fmaxf(0.f, MARGIN_ + s[k][tid] - diag[tid]));
            }
        }
        total = m1 + m2;
    }
    for (int off = 32; off > 0; off >>= 1) total += __shfl_down(total, off);
    if (tid == 0) out[0] = total;
}

extern "C" void kernel_launch(void* const* d_in, const int* in_sizes, int n_in,
                              void* d_out, int out_size, void* d_ws, size_t ws_size,
                              hipStream_t stream) {
    const float* img    = (const float*)d_in[0];
    const float* cap    = (const float*)d_in[1];
    const int*   lens   = (const int*)d_in[2];
    const float* w_lin  = (const float*)d_in[3];
    const float* b_lin  = (const float*)d_in[4];
    const float* w_gate = (const float*)d_in[5];
    const float* b_gate = (const float*)d_in[6];
    float* out = (float*)d_out;

    char* ws = (char*)d_ws;
    const size_t QB = 67108864;                    // bytes per (C,W,I,D) fp16 buffer
    f16* qA    = (f16*)(ws);
    f16* qB    = (f16*)(ws + QB);
    f16* wcb   = (f16*)(ws + 2 * QB);
    f16* capH  = (f16*)(ws + 3 * QB);              // 2 MB
    f16* wlinH = (f16*)(ws + 3 * QB + 2097152);    // 4 MB
    f16* wgateH= (f16*)(ws + 3 * QB + 6291456);    // 4 MB
    float* score = (float*)(ws + 3 * QB + 10485760);

    hipMemsetAsync(score, 0, C_ * I_ * sizeof(float), stream);
    convert_kernel<<<dim3(5120), dim3(256), 0, stream>>>(cap, w_lin, w_gate, capH, wlinH, wgateH);

    // iter 0
    attn_kernel<<<dim3(C_ * I_), dim3(256), 0, stream>>>(img, cap, (const __half*)0, lens, (__half*)wcb, score, 1);
    mlp_kernel<<<dim3(256, 16), dim3(256), 0, stream>>>(cap, capH, (const f16*)0, wcb, wlinH, wgateH, b_lin, b_gate, qA, lens, 1);
    // iter 1
    attn_kernel<<<dim3(C_ * I_), dim3(256), 0, stream>>>(img, cap, (const __half*)qA, lens, (__half*)wcb, score, 0);
    mlp_kernel<<<dim3(256, 16), dim3(256), 0, stream>>>(cap, capH, qA, wcb, wlinH, wgateH, b_lin, b_gate, qB, lens, 0);
    // iter 2 (q update dead)
    attn_kernel<<<dim3(C_ * I_), dim3(256), 0, stream>>>(img, cap, (const __half*)qB, lens, (__half*)wcb, score, 0);

    loss_kernel<<<dim3(1), dim3(64), 0, stream>>>(score, out);
}

// Round 4
// 815.910 us; speedup vs baseline: 14.8230x; 1.7339x over previous
//
#include <hip/hip_runtime.h>
#include <hip/hip_fp16.h>

#define C_ 32
#define I_ 32
#define W_ 32
#define R_ 36
#define D_ 1024
#define EPS_ 1e-8f
#define LAMBDA_ 9.0f
#define MARGIN_ 0.2f

typedef _Float16 f16;
typedef f16 half8 __attribute__((ext_vector_type(8)));
typedef f16 f16x4 __attribute__((ext_vector_type(4)));
typedef float f32x4 __attribute__((ext_vector_type(4)));

__device__ __forceinline__ void gload16(const void* g, void* l) {
    __builtin_amdgcn_global_load_lds((const __attribute__((address_space(1))) void*)g,
                                     (__attribute__((address_space(3))) void*)l, 16, 0, 0);
}

// fp32 -> fp16 of cap, w_lin, w_gate, img (one float4 per thread)
__global__ __launch_bounds__(256) void convert_kernel(
    const float* __restrict__ cap, const float* __restrict__ wl, const float* __restrict__ wg,
    const float* __restrict__ img,
    f16* __restrict__ capH, f16* __restrict__ wlH, f16* __restrict__ wgH, f16* __restrict__ imgH)
{
    const int t = blockIdx.x * 256 + threadIdx.x;   // 1605632 total
    const float* src; f16* dst; int idx;
    if (t < 262144)        { src = cap; dst = capH; idx = t; }
    else if (t < 786432)   { src = wl;  dst = wlH;  idx = t - 262144; }
    else if (t < 1310720)  { src = wg;  dst = wgH;  idx = t - 786432; }
    else                   { src = img; dst = imgH; idx = t - 1310720; }
    float4 v = ((const float4*)src)[idx];
    f16x4 o; o[0] = (f16)v.x; o[1] = (f16)v.y; o[2] = (f16)v.z; o[3] = (f16)v.w;
    *(f16x4*)(dst + (size_t)idx * 4) = o;
}

// imgT (I, D, 64) fp16: imgT[i][d][r] = img[i][r][d], r>=36 zero.
__global__ __launch_bounds__(256) void transpose_kernel(
    const float* __restrict__ img, f16* __restrict__ imgTH)
{
    const int t = blockIdx.x * 256 + threadIdx.x;   // 262144 total
    const int i = t >> 13;
    const int g = (t >> 10) & 7;
    const int d = t & 1023;
    half8 o;
    #pragma unroll
    for (int j = 0; j < 8; j++) {
        const int r = g * 8 + j;
        o[j] = (r < 36) ? (f16)img[((size_t)i * 36 + r) * 1024 + d] : (f16)0.f;
    }
    *(half8*)(imgTH + (((size_t)i * 1024 + d) << 6) + g * 8) = o;
}

// w11Buf[c*32+w] = sum_d cap^2 (exact fp32)
__global__ __launch_bounds__(64) void w11_kernel(const float* __restrict__ cap,
                                                 float* __restrict__ w11Buf)
{
    const int row = blockIdx.x;
    const float* p = cap + (size_t)row * 1024;
    float s = 0.f;
    for (int e = threadIdx.x; e < 1024; e += 64) { float v = p[e]; s += v * v; }
    for (int off = 32; off > 0; off >>= 1) s += __shfl_down(s, off);
    if (threadIdx.x == 0) w11Buf[row] = s;
}

// One WG per (c,i), 4 waves. MFMA attn -> softmax -> MFMA wc -> cos -> score.
__global__ __launch_bounds__(256) void attn_kernel(
    const f16* __restrict__ imgH,       // (I*36 + pad, D)
    const f16* __restrict__ imgTH,      // (I, D, 64)
    const f16* __restrict__ capH,       // (C, W, D)
    const f16* __restrict__ qcur,       // (C,W,I,D), unused if iter0
    const float* __restrict__ w11Buf,   // (C*W)
    const int* __restrict__ lens,
    f16* __restrict__ wc_out,           // (C,W,I,D)
    float* __restrict__ score,          // (C,I)
    const int iter0, const int store_wc)
{
    __shared__ f16 sPA[2][10240];       // per buf: img[48][128] then q[32][128]
    __shared__ f16 sSmT[2048];          // smT [32][64], chunk-swizzled
    __shared__ float sAttn[36][33];
    __shared__ float sNrm[36];
    __shared__ float sW12[4][32];
    __shared__ float sW22[4][32];

    const int ci = blockIdx.x;
    const int c  = ci >> 5;
    const int i  = ci & 31;
    const int len = lens[c];
    const int tid = threadIdx.x;
    const int lane = tid & 63;
    const int wv = tid >> 6;
    const int i36 = i * 36;

    // ---------------- Phase A: attn = img_i (48x1024, pad rows garbage) . q^T
    f32x4 accA[2] = {{0.f,0.f,0.f,0.f},{0.f,0.f,0.f,0.f}};

    // staging: 20 gload16 per chunk (12 img rows-of-4, 8 q rows-of-4)
    auto stageA = [&](int b, int k0) {
        for (int g = wv; g < 20; g += 4) {
            f16* dst; const f16* src;
            if (g < 12) {
                const int row = g * 4 + (lane >> 4);
                dst = &sPA[b][g * 512];
                src = imgH + (size_t)(i36 + row) * 1024 + k0 + (((lane & 15) ^ (row & 7)) << 3);
            } else {
                const int w = (g - 12) * 4 + (lane >> 4);
                dst = &sPA[b][6144 + (g - 12) * 512];
                src = (iter0 ? (capH + (size_t)(c * 32 + w) * 1024)
                             : (qcur + (size_t)((c * 32 + w) * 32 + i) * 1024))
                      + k0 + (((lane & 15) ^ (w & 7)) << 3);
            }
            gload16(src, dst);
        }
    };

    stageA(0, 0);
    __syncthreads();
    int cur = 0;
    for (int kc = 0; kc < 8; kc++) {
        if (kc < 7) stageA(cur ^ 1, (kc + 1) * 128);
        if (wv < 3) {
            #pragma unroll
            for (int ks = 0; ks < 4; ks++) {
                const int arow = wv * 16 + (lane & 15);
                const half8 af = *(const half8*)&sPA[cur][arow * 128 + ((((ks << 2) | (lane >> 4)) ^ (arow & 7)) << 3)];
                #pragma unroll
                for (int nt = 0; nt < 2; nt++) {
                    const int brow = nt * 16 + (lane & 15);
                    const half8 bf = *(const half8*)&sPA[cur][6144 + brow * 128 + ((((ks << 2) | (lane >> 4)) ^ (brow & 7)) << 3)];
                    accA[nt] = __builtin_amdgcn_mfma_f32_16x16x32_f16(af, bf, accA[nt], 0, 0, 0);
                }
            }
        }
        __syncthreads();
        cur ^= 1;
    }

    // leaky relu -> sAttn (r<36 only)
    if (wv < 3) {
        #pragma unroll
        for (int nt = 0; nt < 2; nt++) {
            #pragma unroll
            for (int r = 0; r < 4; r++) {
                const int rr = wv * 16 + (lane >> 4) * 4 + r;
                if (rr < 36) {
                    float v = accA[nt][r];
                    sAttn[rr][nt * 16 + (lane & 15)] = (v >= 0.f) ? v : 0.1f * v;
                }
            }
        }
    }
    __syncthreads();

    if (tid < 36) {
        float s = 0.f;
        for (int w = 0; w < len; w++) { float v = sAttn[tid][w]; s += v * v; }
        sNrm[tid] = sqrtf(s) + EPS_;
    }
    __syncthreads();

    // softmax over r per w; write smT fp16 swizzled; zero pads and masked rows
    if (tid < 32) {
        if (tid < len) {
            float vals[36]; float m = -1e30f;
            #pragma unroll
            for (int r = 0; r < 36; r++) {
                float v = (sAttn[r][tid] / sNrm[r]) * LAMBDA_;
                vals[r] = v; m = fmaxf(m, v);
            }
            float sum = 0.f;
            #pragma unroll
            for (int r = 0; r < 36; r++) { float e = __expf(vals[r] - m); sum += e; vals[r] = e; }
            const float inv = 1.0f / sum;
            #pragma unroll
            for (int r = 0; r < 64; r++) {
                const int off = tid * 64 + ((((r >> 3) ^ (tid & 7)) << 3) | (r & 7));
                sSmT[off] = (r < 36) ? (f16)(vals[r] * inv) : (f16)0.f;
            }
        } else {
            #pragma unroll
            for (int r = 0; r < 64; r++) sSmT[tid * 64 + r] = (f16)0.f;
        }
    }
    __syncthreads();

    // ---------------- Phase B: wc = smT (32x64) . imgT^T ; per-wave 16 d-tiles
    float w12L[2][4], w22L[2][4];
    #pragma unroll
    for (int mt = 0; mt < 2; mt++)
        #pragma unroll
        for (int r = 0; r < 4; r++) { w12L[mt][r] = 0.f; w22L[mt][r] = 0.f; }

    half8 af[2][2];
    #pragma unroll
    for (int mt = 0; mt < 2; mt++)
        #pragma unroll
        for (int ks = 0; ks < 2; ks++) {
            const int row = mt * 16 + (lane & 15);
            af[mt][ks] = *(const half8*)&sSmT[row * 64 + ((((ks << 2) | (lane >> 4)) ^ (row & 7)) << 3)];
        }

    const f16* imgTbase = imgTH + (((size_t)i) << 16);   // i*1024*64
    for (int t = 0; t < 16; t++) {
        const int nt = t * 4 + wv;
        const int d = nt * 16 + (lane & 15);
        const half8 bf0 = *(const half8*)(imgTbase + ((size_t)d << 6) + ((lane >> 4) << 3));
        const half8 bf1 = *(const half8*)(imgTbase + ((size_t)d << 6) + 32 + ((lane >> 4) << 3));
        f32x4 acc[2] = {{0.f,0.f,0.f,0.f},{0.f,0.f,0.f,0.f}};
        #pragma unroll
        for (int mt = 0; mt < 2; mt++) {
            acc[mt] = __builtin_amdgcn_mfma_f32_16x16x32_f16(af[mt][0], bf0, acc[mt], 0, 0, 0);
            acc[mt] = __builtin_amdgcn_mfma_f32_16x16x32_f16(af[mt][1], bf1, acc[mt], 0, 0, 0);
        }
        #pragma unroll
        for (int mt = 0; mt < 2; mt++) {
            #pragma unroll
            for (int r = 0; r < 4; r++) {
                const int w = mt * 16 + (lane >> 4) * 4 + r;
                if (w < len) {
                    const float v = acc[mt][r];
                    const float cp = (float)capH[(size_t)(c * 32 + w) * 1024 + d];
                    w12L[mt][r] += cp * v;
                    w22L[mt][r] += v * v;
                    if (store_wc) wc_out[((size_t)((c * 32 + w) * 32) + i) * 1024 + d] = (f16)v;
                }
            }
        }
    }

    // reduce over the 16 d-lanes within the wave
    #pragma unroll
    for (int mask = 1; mask <= 8; mask <<= 1) {
        #pragma unroll
        for (int mt = 0; mt < 2; mt++)
            #pragma unroll
            for (int r = 0; r < 4; r++) {
                w12L[mt][r] += __shfl_xor(w12L[mt][r], mask);
                w22L[mt][r] += __shfl_xor(w22L[mt][r], mask);
            }
    }
    // spill per-wave partials (each wave covered 1/4 of d) -> LDS
    if ((lane & 15) == 0) {
        #pragma unroll
        for (int mt = 0; mt < 2; mt++)
            #pragma unroll
            for (int r = 0; r < 4; r++) {
                const int w = mt * 16 + (lane >> 4) * 4 + r;
                sW12[wv][w] = w12L[mt][r];
                sW22[wv][w] = w22L[mt][r];
            }
    }
    __syncthreads();
    // sum the 4 wave-partials per w, THEN cosine (full-d sums)
    if (tid < 32) {
        const int w = tid;
        float part = 0.f;
        if (w < len) {
            const float a = sW12[0][w] + sW12[1][w] + sW12[2][w] + sW12[3][w];
            const float b = sW22[0][w] + sW22[1][w] + sW22[2][w] + sW22[3][w];
            part = a / fmaxf(sqrtf(w11Buf[c * 32 + w]) * sqrtf(b), EPS_);
        }
        for (int off = 16; off > 0; off >>= 1) part += __shfl_down(part, off);
        if (tid == 0) score[ci] += part / (float)len;
    }
}

// MFMA fp16 gating MLP, double-buffered 1-barrier K-loop + XCD-chunked swizzle.
__global__ __launch_bounds__(256) void mlp_kernel(
    const float* __restrict__ cap,
    const f16* __restrict__ capH,
    const f16* __restrict__ qcur,       // (C,W,I,D)
    const f16* __restrict__ wcb,        // (C,W,I,D)
    const f16* __restrict__ wlinH, const f16* __restrict__ wgateH,
    const float* __restrict__ b_lin, const float* __restrict__ b_gate,
    f16* __restrict__ qnext,            // (C,W,I,D)
    const int* __restrict__ lens,
    const int iter0)
{
    // bijective XCD swizzle: consecutive logical L on one XCD; jt slow in chunk
    const int bid = blockIdx.x;               // 0..4095
    const int L = (bid & 7) * 512 + (bid >> 3);
    const int jt = L >> 8;                    // 0..15
    const int cm = L & 255;
    const int c  = cm >> 3;
    const int mt = cm & 7;
    const int len = lens[c];
    if (mt * 4 >= len) return;
    const int m0 = c * 1024 + mt * 128;

    __shared__ char sMem[65536];              // 2 bufs x (A 16K | B 16K)

    const int tid = threadIdx.x;
    const int lane = tid & 63;
    const int wv = tid >> 6;
    const int wm = wv >> 1;
    const int wn = wv & 1;
    const int rsub = lane >> 3;
    const int ch = lane & 7;

    const f16* a1p[4]; const f16* a2p[4]; const f16* bp[4];
    int ldsAoff[4], ldsBoff[4];
    #pragma unroll
    for (int t = 0; t < 4; t++) {
        const int row = wv * 32 + t * 8 + rsub;
        const int m = m0 + row;
        const int sw = ((ch ^ (row & 7)) << 3);
        a1p[t] = (iter0 ? (capH + ((size_t)(m >> 5) << 10)) : (qcur + ((size_t)m << 10))) + sw;
        a2p[t] = wcb + ((size_t)m << 10) + sw;
        const int n = row;
        const f16* wrow = (n < 64) ? (wlinH + ((size_t)(jt * 64 + n) << 11))
                                   : (wgateH + ((size_t)(jt * 64 + n - 64) << 11));
        bp[t] = wrow + ((ch ^ (n & 7)) << 3);
        ldsAoff[t] = wv * 4096 + t * 1024;
        ldsBoff[t] = 16384 + wv * 4096 + t * 1024;
    }

    f32x4 acc[4][4];
    #pragma unroll
    for (int a = 0; a < 4; a++)
        #pragma unroll
        for (int b = 0; b < 4; b++)
            acc[a][b] = (f32x4){0.f, 0.f, 0.f, 0.f};

    // prologue: stage k-chunk 0 into buf 0
    {
        char* nb = sMem;
        #pragma unroll
        for (int t = 0; t < 4; t++) gload16(a1p[t], nb + ldsAoff[t]);
        #pragma unroll
        for (int t = 0; t < 4; t++) gload16(bp[t], nb + ldsBoff[t]);
    }
    __syncthreads();

    int cur = 0;
    for (int ks = 0; ks < 32; ks++) {
        if (ks < 31) {
            const int kk = (ks + 1) * 64;
            char* nb = sMem + ((cur ^ 1) << 15);
            if (kk < 1024) {
                #pragma unroll
                for (int t = 0; t < 4; t++) gload16(a1p[t] + kk, nb + ldsAoff[t]);
            } else {
                #pragma unroll
                for (int t = 0; t < 4; t++) gload16(a2p[t] + (kk - 1024), nb + ldsAoff[t]);
            }
            #pragma unroll
            for (int t = 0; t < 4; t++) gload16(bp[t] + kk, nb + ldsBoff[t]);
        }
        const char* cb = sMem + (cur << 15);
        #pragma unroll
        for (int ksub = 0; ksub < 2; ksub++) {
            const int kch = ksub * 4 + (lane >> 4);
            half8 afr[4], bfr[4];
            #pragma unroll
            for (int tm = 0; tm < 4; tm++) {
                const int row = wm * 64 + tm * 16 + (lane & 15);
                afr[tm] = *(const half8*)(cb + row * 128 + ((kch ^ (row & 7)) << 4));
            }
            #pragma unroll
            for (int tn = 0; tn < 4; tn++) {
                const int n = ((tn >> 1) << 6) + wn * 32 + ((tn & 1) << 4) + (lane & 15);
                bfr[tn] = *(const half8*)(cb + 16384 + n * 128 + ((kch ^ (n & 7)) << 4));
            }
            #pragma unroll
            for (int tm = 0; tm < 4; tm++)
                #pragma unroll
                for (int tn = 0; tn < 4; tn++)
                    acc[tm][tn] = __builtin_amdgcn_mfma_f32_16x16x32_f16(afr[tm], bfr[tn], acc[tm][tn], 0, 0, 0);
        }
        __syncthreads();
        cur ^= 1;
    }

    // epilogue
    const int j0 = jt * 64 + wn * 32 + (lane & 15);
    const float bl0 = b_lin[j0],  bl1 = b_lin[j0 + 16];
    const float bg0 = b_gate[j0], bg1 = b_gate[j0 + 16];
    #pragma unroll
    for (int tm = 0; tm < 4; tm++) {
        #pragma unroll
        for (int tp = 0; tp < 2; tp++) {
            const f32x4 ha = acc[tm][tp];
            const f32x4 ga = acc[tm][tp + 2];
            const int j = j0 + tp * 16;
            const float bl = tp ? bl1 : bl0;
            const float bg = tp ? bg1 : bg0;
            #pragma unroll
            for (int r = 0; r < 4; r++) {
                const int m = m0 + wm * 64 + tm * 16 + (lane >> 4) * 4 + r;
                const int w = (m >> 5) & 31;
                if (w < len) {
                    const float hp = ha[r] + bl;
                    const float gp = ga[r] + bg;
                    const float g = 1.f / (1.f + __expf(-gp));
                    const float h = tanhf(hp);
                    const float qold = iter0 ? cap[((size_t)(m >> 5) << 10) + j]
                                             : (float)qcur[((size_t)m << 10) + j];
                    qnext[((size_t)m << 10) + j] = (f16)(qold * g + h * (1.f - g));
                }
            }
        }
    }
}

__global__ __launch_bounds__(64) void loss_kernel(const float* __restrict__ score,
                                                  float* __restrict__ out)
{
    __shared__ float s[32][33];
    __shared__ float diag[32];
    const int tid = threadIdx.x;
    for (int idx = tid; idx < 1024; idx += 64) s[idx >> 5][idx & 31] = score[idx];
    __syncthreads();
    if (tid < 32) diag[tid] = s[tid][tid];
    __syncthreads();
    float total = 0.f;
    if (tid < 32) {
        float m1 = 0.f, m2 = 0.f;
        for (int k = 0; k < 32; k++) {
            if (k != tid) {
                m1 = fmaxf(m1, fmaxf(0.f, MARGIN_ + s[tid][k] - diag[tid]));
                m2 = fmaxf(m2, fmaxf(0.f, MARGIN_ + s[k][tid] - diag[tid]));
            }
        }
        total = m1 + m2;
    }
    for (int off = 32; off > 0; off >>= 1) total += __shfl_down(total, off);
    if (tid == 0) out[0] = total;
}

extern "C" void kernel_launch(void* const* d_in, const int* in_sizes, int n_in,
                              void* d_out, int out_size, void* d_ws, size_t ws_size,
                              hipStream_t stream) {
    const float* img    = (const float*)d_in[0];
    const float* cap    = (const float*)d_in[1];
    const int*   lens   = (const int*)d_in[2];
    const float* w_lin  = (const float*)d_in[3];
    const float* b_lin  = (const float*)d_in[4];
    const float* w_gate = (const float*)d_in[5];
    const float* b_gate = (const float*)d_in[6];
    float* out = (float*)d_out;

    char* ws = (char*)d_ws;
    f16* qA     = (f16*)(ws);                        // 64 MB
    f16* qB     = (f16*)(ws + 67108864);             // 64 MB
    f16* wcb    = (f16*)(ws + 134217728);            // 64 MB
    f16* capH   = (f16*)(ws + 201326592);            // 2 MB
    f16* wlinH  = (f16*)(ws + 203423744);            // 4 MB
    f16* wgateH = (f16*)(ws + 207618048);            // 4 MB
    f16* imgH   = (f16*)(ws + 211812352);            // 2.4 MB ((32*36+16)*1024*2)
    f16* imgTH  = (f16*)(ws + 214204416);            // 4 MB (32*1024*64*2)
    float* w11Buf = (float*)(ws + 218398720);        // 4 KB
    float* score  = (float*)(ws + 218402816);        // 4 KB

    hipMemsetAsync(score, 0, C_ * I_ * sizeof(float), stream);
    convert_kernel<<<dim3(6272), dim3(256), 0, stream>>>(cap, w_lin, w_gate, img, capH, wlinH, wgateH, imgH);
    transpose_kernel<<<dim3(1024), dim3(256), 0, stream>>>(img, imgTH);
    w11_kernel<<<dim3(1024), dim3(64), 0, stream>>>(cap, w11Buf);

    // iter 0
    attn_kernel<<<dim3(1024), dim3(256), 0, stream>>>(imgH, imgTH, capH, (const f16*)0, w11Buf, lens, wcb, score, 1, 1);
    mlp_kernel<<<dim3(4096), dim3(256), 0, stream>>>(cap, capH, (const f16*)0, wcb, wlinH, wgateH, b_lin, b_gate, qA, lens, 1);
    // iter 1
    attn_kernel<<<dim3(1024), dim3(256), 0, stream>>>(imgH, imgTH, capH, qA, w11Buf, lens, wcb, score, 0, 1);
    mlp_kernel<<<dim3(4096), dim3(256), 0, stream>>>(cap, capH, qA, wcb, wlinH, wgateH, b_lin, b_gate, qB, lens, 0);
    // iter 2 (q update dead; wc stores skipped)
    attn_kernel<<<dim3(1024), dim3(256), 0, stream>>>(imgH, imgTH, capH, qB, w11Buf, lens, wcb, score, 0, 0);

    loss_kernel<<<dim3(1), dim3(64), 0, stream>>>(score, out);
}

// Round 5
// 642.897 us; speedup vs baseline: 18.8121x; 1.2691x over previous
//
#include <hip/hip_runtime.h>
#include <hip/hip_fp16.h>

#define C_ 32
#define I_ 32
#define W_ 32
#define R_ 36
#define D_ 1024
#define EPS_ 1e-8f
#define LAMBDA_ 9.0f
#define MARGIN_ 0.2f

typedef _Float16 f16;
typedef f16 half8 __attribute__((ext_vector_type(8)));
typedef f16 f16x4 __attribute__((ext_vector_type(4)));
typedef float f32x4 __attribute__((ext_vector_type(4)));

__device__ __forceinline__ void gload16(const void* g, void* l) {
    __builtin_amdgcn_global_load_lds((const __attribute__((address_space(1))) void*)g,
                                     (__attribute__((address_space(3))) void*)l, 16, 0, 0);
}

// fp32 -> fp16 of cap, w_lin, w_gate, img (one float4 per thread)
__global__ __launch_bounds__(256) void convert_kernel(
    const float* __restrict__ cap, const float* __restrict__ wl, const float* __restrict__ wg,
    const float* __restrict__ img,
    f16* __restrict__ capH, f16* __restrict__ wlH, f16* __restrict__ wgH, f16* __restrict__ imgH)
{
    const int t = blockIdx.x * 256 + threadIdx.x;   // 1605632 total
    const float* src; f16* dst; int idx;
    if (t < 262144)        { src = cap; dst = capH; idx = t; }
    else if (t < 786432)   { src = wl;  dst = wlH;  idx = t - 262144; }
    else if (t < 1310720)  { src = wg;  dst = wgH;  idx = t - 786432; }
    else                   { src = img; dst = imgH; idx = t - 1310720; }
    float4 v = ((const float4*)src)[idx];
    f16x4 o; o[0] = (f16)v.x; o[1] = (f16)v.y; o[2] = (f16)v.z; o[3] = (f16)v.w;
    *(f16x4*)(dst + (size_t)idx * 4) = o;
}

// imgT (I, D, 64) fp16: imgT[i][d][r] = img[i][r][d], r>=36 zero.
__global__ __launch_bounds__(256) void transpose_kernel(
    const float* __restrict__ img, f16* __restrict__ imgTH)
{
    const int t = blockIdx.x * 256 + threadIdx.x;   // 262144 total
    const int i = t >> 13;
    const int g = (t >> 10) & 7;
    const int d = t & 1023;
    half8 o;
    #pragma unroll
    for (int j = 0; j < 8; j++) {
        const int r = g * 8 + j;
        o[j] = (r < 36) ? (f16)img[((size_t)i * 36 + r) * 1024 + d] : (f16)0.f;
    }
    *(half8*)(imgTH + (((size_t)i * 1024 + d) << 6) + g * 8) = o;
}

// w11Buf[c*32+w] = sum_d cap^2 (exact fp32)
__global__ __launch_bounds__(64) void w11_kernel(const float* __restrict__ cap,
                                                 float* __restrict__ w11Buf)
{
    const int row = blockIdx.x;
    const float* p = cap + (size_t)row * 1024;
    float s = 0.f;
    for (int e = threadIdx.x; e < 1024; e += 64) { float v = p[e]; s += v * v; }
    for (int off = 32; off > 0; off >>= 1) s += __shfl_down(s, off);
    if (threadIdx.x == 0) w11Buf[row] = s;
}

// imgW2T[i][j][r] = sum_d img[i][r][d] * Wpair2[j][d]   (j<1024: w_lin col-half2,
// else w_gate). Layout (I, 2048, 64), r>=36 zeroed. Block: (jt 0..15, i 0..31).
__global__ __launch_bounds__(256) void imgw2t_kernel(
    const f16* __restrict__ wlinH, const f16* __restrict__ wgateH,
    const f16* __restrict__ imgH, f16* __restrict__ imgW2T)
{
    const int jt = blockIdx.x;
    const int i  = blockIdx.y;
    __shared__ f16 sA[128 * 64];    // rows of 128B, chunk-swizzled
    __shared__ f16 sB[64 * 64];
    const int tid = threadIdx.x, lane = tid & 63, wv = tid >> 6;
    const int wm = wv >> 1, wn = wv & 1;
    f32x4 acc[4][2];
    #pragma unroll
    for (int a = 0; a < 4; a++) { acc[a][0] = (f32x4){0,0,0,0}; acc[a][1] = (f32x4){0,0,0,0}; }

    for (int ks = 0; ks < 16; ks++) {
        const int kk = ks * 64;
        __syncthreads();
        #pragma unroll
        for (int p = 0; p < 4; p++) {
            const int u = tid + p * 256;
            const int row = u >> 3, ch = u & 7;
            const int jr = jt * 128 + row;
            const f16* src = ((jr < 1024) ? (wlinH + (size_t)jr * 2048)
                                          : (wgateH + (size_t)(jr - 1024) * 2048))
                             + 1024 + kk + ((ch ^ (row & 7)) << 3);
            gload16(src, (char*)sA + u * 16);
        }
        #pragma unroll
        for (int p = 0; p < 2; p++) {
            const int u = tid + p * 256;
            const int row = u >> 3, ch = u & 7;
            const f16* src = imgH + (size_t)(i * 36 + row) * 1024 + kk + ((ch ^ (row & 7)) << 3);
            gload16(src, (char*)sB + u * 16);
        }
        __syncthreads();
        #pragma unroll
        for (int ksub = 0; ksub < 2; ksub++) {
            const int kch = (ksub << 2) | (lane >> 4);
            half8 af[4], bf[2];
            #pragma unroll
            for (int tm = 0; tm < 4; tm++) {
                const int row = wm * 64 + tm * 16 + (lane & 15);
                af[tm] = *(const half8*)((const char*)sA + row * 128 + ((kch ^ (row & 7)) << 4));
            }
            #pragma unroll
            for (int tn = 0; tn < 2; tn++) {
                const int row = wn * 32 + tn * 16 + (lane & 15);
                bf[tn] = *(const half8*)((const char*)sB + row * 128 + ((kch ^ (row & 7)) << 4));
            }
            #pragma unroll
            for (int tm = 0; tm < 4; tm++)
                #pragma unroll
                for (int tn = 0; tn < 2; tn++)
                    acc[tm][tn] = __builtin_amdgcn_mfma_f32_16x16x32_f16(af[tm], bf[tn], acc[tm][tn], 0, 0, 0);
        }
    }
    #pragma unroll
    for (int tm = 0; tm < 4; tm++)
        #pragma unroll
        for (int tn = 0; tn < 2; tn++)
            #pragma unroll
            for (int r = 0; r < 4; r++) {
                const int j = jt * 128 + wm * 64 + tm * 16 + (lane >> 4) * 4 + r;
                const int rc = wn * 32 + tn * 16 + (lane & 15);
                imgW2T[((size_t)i * 2048 + j) * 64 + rc] = (rc < 36) ? (f16)acc[tm][tn][r] : (f16)0.f;
            }
}

// One WG per (c,i), 4 waves. MFMA attn -> softmax -> MFMA {wc->cos, pre} -> score.
__global__ __launch_bounds__(256) void attn_kernel(
    const f16* __restrict__ imgH,       // (>=I*36 rows, D)
    const f16* __restrict__ imgTH,      // (I, D, 64)
    const f16* __restrict__ imgW2T,     // (I, 2048, 64)
    const f16* __restrict__ capH,       // (C, W, D)
    const f16* __restrict__ qcur,       // (C,W,I,D), unused if iter0
    const float* __restrict__ w11Buf,
    const int* __restrict__ lens,
    f16* __restrict__ preLin,           // (C,W,I,1024)
    f16* __restrict__ preGate,          // (C,W,I,1024)
    float* __restrict__ score,          // (C,I)
    const int iter0, const int do_pre)
{
    __shared__ f16 sPA[2][10240];       // per buf: img[48][128] then q[32][128]
    __shared__ f16 sSmT[2048];          // smT [32][64], chunk-swizzled
    __shared__ float sAttn[36][33];
    __shared__ float sNrm[36];
    __shared__ float sW12[4][32];
    __shared__ float sW22[4][32];

    const int bid = blockIdx.x;
    const int c  = bid & 31;            // c fast: consecutive blocks share i
    const int i  = bid >> 5;
    const int len = lens[c];
    const int tid = threadIdx.x;
    const int lane = tid & 63;
    const int wv = tid >> 6;
    const int i36 = i * 36;

    const f16* qB = iter0 ? (const f16*)0 : (qcur + ((size_t)c * 1024 + i) * 1024);

    f32x4 accA[2] = {{0.f,0.f,0.f,0.f},{0.f,0.f,0.f,0.f}};

    auto stageA = [&](int b, int k0) {
        for (int g = wv; g < 20; g += 4) {
            f16* dst; const f16* src;
            if (g < 12) {
                const int row = g * 4 + (lane >> 4);
                dst = &sPA[b][g * 512];
                src = imgH + (size_t)(i36 + row) * 1024 + k0 + (((lane & 15) ^ (row & 7)) << 3);
            } else {
                const int w = (g - 12) * 4 + (lane >> 4);
                dst = &sPA[b][6144 + (g - 12) * 512];
                src = (iter0 ? (capH + (size_t)(c * 32 + w) * 1024)
                             : (qB + (size_t)w * (32 * 1024)))
                      + k0 + (((lane & 15) ^ (w & 7)) << 3);
            }
            gload16(src, dst);
        }
    };

    stageA(0, 0);
    __syncthreads();
    int cur = 0;
    for (int kc = 0; kc < 8; kc++) {
        if (kc < 7) stageA(cur ^ 1, (kc + 1) * 128);
        if (wv < 3) {
            #pragma unroll
            for (int ks = 0; ks < 4; ks++) {
                const int arow = wv * 16 + (lane & 15);
                const half8 af = *(const half8*)&sPA[cur][arow * 128 + ((((ks << 2) | (lane >> 4)) ^ (arow & 7)) << 3)];
                #pragma unroll
                for (int nt = 0; nt < 2; nt++) {
                    const int brow = nt * 16 + (lane & 15);
                    const half8 bf = *(const half8*)&sPA[cur][6144 + brow * 128 + ((((ks << 2) | (lane >> 4)) ^ (brow & 7)) << 3)];
                    accA[nt] = __builtin_amdgcn_mfma_f32_16x16x32_f16(af, bf, accA[nt], 0, 0, 0);
                }
            }
        }
        __syncthreads();
        cur ^= 1;
    }

    if (wv < 3) {
        #pragma unroll
        for (int nt = 0; nt < 2; nt++) {
            #pragma unroll
            for (int r = 0; r < 4; r++) {
                const int rr = wv * 16 + (lane >> 4) * 4 + r;
                if (rr < 36) {
                    float v = accA[nt][r];
                    sAttn[rr][nt * 16 + (lane & 15)] = (v >= 0.f) ? v : 0.1f * v;
                }
            }
        }
    }
    __syncthreads();

    if (tid < 36) {
        float s = 0.f;
        for (int w = 0; w < len; w++) { float v = sAttn[tid][w]; s += v * v; }
        sNrm[tid] = sqrtf(s) + EPS_;
    }
    __syncthreads();

    if (tid < 32) {
        if (tid < len) {
            float vals[36]; float m = -1e30f;
            #pragma unroll
            for (int r = 0; r < 36; r++) {
                float v = (sAttn[r][tid] / sNrm[r]) * LAMBDA_;
                vals[r] = v; m = fmaxf(m, v);
            }
            float sum = 0.f;
            #pragma unroll
            for (int r = 0; r < 36; r++) { float e = __expf(vals[r] - m); sum += e; vals[r] = e; }
            const float inv = 1.0f / sum;
            #pragma unroll
            for (int r = 0; r < 64; r++) {
                const int off = tid * 64 + ((((r >> 3) ^ (tid & 7)) << 3) | (r & 7));
                sSmT[off] = (r < 36) ? (f16)(vals[r] * inv) : (f16)0.f;
            }
        } else {
            #pragma unroll
            for (int r = 0; r < 64; r++) sSmT[tid * 64 + r] = (f16)0.f;
        }
    }
    __syncthreads();

    // A-frags (sm rows) shared by wc and pre parts
    half8 af[2][2];
    #pragma unroll
    for (int mt = 0; mt < 2; mt++)
        #pragma unroll
        for (int ks = 0; ks < 2; ks++) {
            const int row = mt * 16 + (lane & 15);
            af[mt][ks] = *(const half8*)&sSmT[row * 64 + ((((ks << 2) | (lane >> 4)) ^ (row & 7)) << 3)];
        }

    // ---- wc part: cos numerator/denominator only (wc never materialized)
    float w12L[2][4], w22L[2][4];
    #pragma unroll
    for (int mt = 0; mt < 2; mt++)
        #pragma unroll
        for (int r = 0; r < 4; r++) { w12L[mt][r] = 0.f; w22L[mt][r] = 0.f; }

    const f16* imgTbase = imgTH + (((size_t)i) << 16);
    for (int t = 0; t < 16; t++) {
        const int nt = t * 4 + wv;
        const int d = nt * 16 + (lane & 15);
        const half8 bf0 = *(const half8*)(imgTbase + ((size_t)d << 6) + ((lane >> 4) << 3));
        const half8 bf1 = *(const half8*)(imgTbase + ((size_t)d << 6) + 32 + ((lane >> 4) << 3));
        f32x4 acc[2] = {{0.f,0.f,0.f,0.f},{0.f,0.f,0.f,0.f}};
        #pragma unroll
        for (int mt = 0; mt < 2; mt++) {
            acc[mt] = __builtin_amdgcn_mfma_f32_16x16x32_f16(af[mt][0], bf0, acc[mt], 0, 0, 0);
            acc[mt] = __builtin_amdgcn_mfma_f32_16x16x32_f16(af[mt][1], bf1, acc[mt], 0, 0, 0);
        }
        #pragma unroll
        for (int mt = 0; mt < 2; mt++) {
            #pragma unroll
            for (int r = 0; r < 4; r++) {
                const int w = mt * 16 + (lane >> 4) * 4 + r;
                if (w < len) {
                    const float v = acc[mt][r];
                    const float cp = (float)capH[(size_t)(c * 32 + w) * 1024 + d];
                    w12L[mt][r] += cp * v;
                    w22L[mt][r] += v * v;
                }
            }
        }
    }

    // ---- pre part: pre = sm @ imgW2T[i]  (N=2048: lin | gate)
    if (do_pre) {
        const f16* w2base = imgW2T + (((size_t)i * 2048) << 6);
        for (int t = 0; t < 32; t++) {
            const int nt = t * 4 + wv;              // 0..127
            const int j = nt * 16 + (lane & 15);    // 0..2047
            const f16* bb = w2base + ((size_t)j << 6);
            const half8 bf0 = *(const half8*)(bb + ((lane >> 4) << 3));
            const half8 bf1 = *(const half8*)(bb + 32 + ((lane >> 4) << 3));
            f32x4 acc[2] = {{0.f,0.f,0.f,0.f},{0.f,0.f,0.f,0.f}};
            #pragma unroll
            for (int mt = 0; mt < 2; mt++) {
                acc[mt] = __builtin_amdgcn_mfma_f32_16x16x32_f16(af[mt][0], bf0, acc[mt], 0, 0, 0);
                acc[mt] = __builtin_amdgcn_mfma_f32_16x16x32_f16(af[mt][1], bf1, acc[mt], 0, 0, 0);
            }
            f16* dstBase = (nt < 64) ? preLin : preGate;
            const int jl = j & 1023;
            #pragma unroll
            for (int mt = 0; mt < 2; mt++) {
                #pragma unroll
                for (int r = 0; r < 4; r++) {
                    const int w = mt * 16 + (lane >> 4) * 4 + r;
                    if (w < len)
                        dstBase[((size_t)((c * 32 + w) * 32 + i) << 10) + jl] = (f16)acc[mt][r];
                }
            }
        }
    }

    // ---- cross-wave reduce for cos/score
    #pragma unroll
    for (int mask = 1; mask <= 8; mask <<= 1) {
        #pragma unroll
        for (int mt = 0; mt < 2; mt++)
            #pragma unroll
            for (int r = 0; r < 4; r++) {
                w12L[mt][r] += __shfl_xor(w12L[mt][r], mask);
                w22L[mt][r] += __shfl_xor(w22L[mt][r], mask);
            }
    }
    if ((lane & 15) == 0) {
        #pragma unroll
        for (int mt = 0; mt < 2; mt++)
            #pragma unroll
            for (int r = 0; r < 4; r++) {
                const int w = mt * 16 + (lane >> 4) * 4 + r;
                sW12[wv][w] = w12L[mt][r];
                sW22[wv][w] = w22L[mt][r];
            }
    }
    __syncthreads();
    if (tid < 32) {
        const int w = tid;
        float part = 0.f;
        if (w < len) {
            const float a = sW12[0][w] + sW12[1][w] + sW12[2][w] + sW12[3][w];
            const float b = sW22[0][w] + sW22[1][w] + sW22[2][w] + sW22[3][w];
            part = a / fmaxf(sqrtf(w11Buf[c * 32 + w]) * sqrtf(b), EPS_);
        }
        for (int off = 16; off > 0; off >>= 1) part += __shfl_down(part, off);
        if (tid == 0) score[c * 32 + i] += part / (float)len;
    }
}

// q-half GEMM.  mode0: capW1 = capH @ W1pair^T (M=1024, raw store).
// mode1: qnext = blend(qA, tanh/sigm(qA@W1^T + pre + b)) (M=32768, len-skip).
// BM=128, BN=256 (128 j x {lin,gate}), BK=32, dbuf, 8 waves (2m x 4n).
__global__ __launch_bounds__(512, 4) void qgemm_kernel(
    const f16* __restrict__ Aptr,
    const f16* __restrict__ wlinH, const f16* __restrict__ wgateH,
    const f16* __restrict__ preLin, const f16* __restrict__ preGate,
    const float* __restrict__ b_lin, const float* __restrict__ b_gate,
    f16* __restrict__ outp,
    const int* __restrict__ lens, const int mode)
{
    const int bid = blockIdx.x;
    const int jt = bid & 7;                 // one jt per XCD (round-robin)
    const int cm = bid >> 3;
    int len = 32;
    if (mode) { len = lens[cm >> 3]; if ((cm & 7) * 4 >= len) return; }
    const int m0 = cm * 128;

    __shared__ char sMem[49152];            // 2 x (A 8K + B 16K)

    const int tid = threadIdx.x;
    const int lane = tid & 63;
    const int wv = tid >> 6;
    const int wm = wv >> 2;                 // 0..1
    const int wn = wv & 3;                  // 0..3

    auto stage = [&](int b, int ks) {
        const int kk = ks * 32;
        char* base = sMem + b * 24576;
        {
            const int row = tid >> 2, kg = tid & 3;
            const f16* src = Aptr + (size_t)(m0 + row) * 1024 + kk + ((kg ^ ((row >> 1) & 3)) << 3);
            gload16(src, base + tid * 16);
        }
        #pragma unroll
        for (int p = 0; p < 2; p++) {
            const int u = tid + p * 512;
            const int row = u >> 2, kg = u & 3;
            const int j = jt * 128 + (row & 127);
            const f16* wsrc = ((row < 128) ? wlinH : wgateH) + (size_t)j * 2048 + kk + ((kg ^ ((row >> 1) & 3)) << 3);
            gload16(wsrc, base + 8192 + u * 16);
        }
    };

    f32x4 acc[4][4];
    #pragma unroll
    for (int a = 0; a < 4; a++)
        #pragma unroll
        for (int b = 0; b < 4; b++)
            acc[a][b] = (f32x4){0.f, 0.f, 0.f, 0.f};

    stage(0, 0);
    __syncthreads();
    int cur = 0;
    for (int ks = 0; ks < 32; ks++) {
        if (ks < 31) stage(cur ^ 1, ks + 1);
        const char* cb = sMem + cur * 24576;
        half8 af[4], bf[4];
        #pragma unroll
        for (int tm = 0; tm < 4; tm++) {
            const int row = wm * 64 + tm * 16 + (lane & 15);
            af[tm] = *(const half8*)(cb + row * 64 + (((lane >> 4) ^ ((row >> 1) & 3)) << 4));
        }
        #pragma unroll
        for (int tn = 0; tn < 4; tn++) {
            const int n = ((tn >> 1) << 7) + wn * 32 + ((tn & 1) << 4) + (lane & 15);
            bf[tn] = *(const half8*)(cb + 8192 + n * 64 + (((lane >> 4) ^ ((n >> 1) & 3)) << 4));
        }
        #pragma unroll
        for (int tm = 0; tm < 4; tm++)
            #pragma unroll
            for (int tn = 0; tn < 4; tn++)
                acc[tm][tn] = __builtin_amdgcn_mfma_f32_16x16x32_f16(af[tm], bf[tn], acc[tm][tn], 0, 0, 0);
        __syncthreads();
        cur ^= 1;
    }

    #pragma unroll
    for (int tm = 0; tm < 4; tm++) {
        #pragma unroll
        for (int tp = 0; tp < 2; tp++) {
            const int j = jt * 128 + wn * 32 + tp * 16 + (lane & 15);   // 0..1023
            if (mode == 0) {
                #pragma unroll
                for (int r = 0; r < 4; r++) {
                    const int m = m0 + wm * 64 + tm * 16 + (lane >> 4) * 4 + r;
                    outp[(size_t)m * 2048 + j] = (f16)acc[tm][tp][r];
                    outp[(size_t)m * 2048 + 1024 + j] = (f16)acc[tm][tp + 2][r];
                }
            } else {
                const float bl = b_lin[j], bg = b_gate[j];
                #pragma unroll
                for (int r = 0; r < 4; r++) {
                    const int m = m0 + wm * 64 + tm * 16 + (lane >> 4) * 4 + r;
                    const int w = (m >> 5) & 31;
                    if (w < len) {
                        const size_t off = ((size_t)m << 10) + j;
                        const float hp = acc[tm][tp][r] + (float)preLin[off] + bl;
                        const float gp = acc[tm][tp + 2][r] + (float)preGate[off] + bg;
                        const float g = 1.f / (1.f + __expf(-gp));
                        const float h = tanhf(hp);
                        const float qold = (float)Aptr[off];
                        outp[off] = (f16)(qold * g + h * (1.f - g));
                    }
                }
            }
        }
    }
}

// iter0 combine: qA = blend(cap, act(capW1 + pre + b)) per active (c,w), all i.
__global__ __launch_bounds__(256) void combine_kernel(
    const float* __restrict__ cap, const f16* __restrict__ capW1,
    const f16* __restrict__ preLin, const f16* __restrict__ preGate,
    const float* __restrict__ b_lin, const float* __restrict__ b_gate,
    f16* __restrict__ qA, const int* __restrict__ lens)
{
    const int bid = blockIdx.x;
    const int c = bid >> 5, w = bid & 31;
    if (w >= lens[c]) return;
    const int tid = threadIdx.x;
    const int j8 = (tid & 127) * 8;
    const int i0 = tid >> 7;
    const size_t cw = (size_t)(c * 32 + w);

    const half8 l8 = *(const half8*)(capW1 + cw * 2048 + j8);
    const half8 g8 = *(const half8*)(capW1 + cw * 2048 + 1024 + j8);
    float bl[8], bg[8], cp[8];
    #pragma unroll
    for (int k = 0; k < 8; k++) {
        bl[k] = b_lin[j8 + k]; bg[k] = b_gate[j8 + k];
        cp[k] = cap[cw * 1024 + j8 + k];
    }
    for (int ii = i0; ii < 32; ii += 2) {
        const size_t m = cw * 32 + ii;
        const half8 pl = *(const half8*)(preLin + (m << 10) + j8);
        const half8 pg = *(const half8*)(preGate + (m << 10) + j8);
        half8 o;
        #pragma unroll
        for (int k = 0; k < 8; k++) {
            const float h = tanhf((float)l8[k] + (float)pl[k] + bl[k]);
            const float g = 1.f / (1.f + __expf(-((float)g8[k] + (float)pg[k] + bg[k])));
            o[k] = (f16)(cp[k] * g + h * (1.f - g));
        }
        *(half8*)(qA + (m << 10) + j8) = o;
    }
}

__global__ __launch_bounds__(64) void loss_kernel(const float* __restrict__ score,
                                                  float* __restrict__ out)
{
    __shared__ float s[32][33];
    __shared__ float diag[32];
    const int tid = threadIdx.x;
    for (int idx = tid; idx < 1024; idx += 64) s[idx >> 5][idx & 31] = score[idx];
    __syncthreads();
    if (tid < 32) diag[tid] = s[tid][tid];
    __syncthreads();
    float total = 0.f;
    if (tid < 32) {
        float m1 = 0.f, m2 = 0.f;
        for (int k = 0; k < 32; k++) {
            if (k != tid) {
                m1 = fmaxf(m1, fmaxf(0.f, MARGIN_ + s[tid][k] - diag[tid]));
                m2 = fmaxf(m2, fmaxf(0.f, MARGIN_ + s[k][tid] - diag[tid]));
            }
        }
        total = m1 + m2;
    }
    for (int off = 32; off > 0; off >>= 1) total += __shfl_down(total, off);
    if (tid == 0) out[0] = total;
}

extern "C" void kernel_launch(void* const* d_in, const int* in_sizes, int n_in,
                              void* d_out, int out_size, void* d_ws, size_t ws_size,
                              hipStream_t stream) {
    const float* img    = (const float*)d_in[0];
    const float* cap    = (const float*)d_in[1];
    const int*   lens   = (const int*)d_in[2];
    const float* w_lin  = (const float*)d_in[3];
    const float* b_lin  = (const float*)d_in[4];
    const float* w_gate = (const float*)d_in[5];
    const float* b_gate = (const float*)d_in[6];
    float* out = (float*)d_out;

    char* ws = (char*)d_ws;
    f16* qA     = (f16*)(ws);                        // 64 MB
    f16* preLin = (f16*)(ws + 67108864);             // 64 MB (qB aliases here)
    f16* preGate= (f16*)(ws + 134217728);            // 64 MB
    f16* capH   = (f16*)(ws + 201326592);            // 2 MB
    f16* wlinH  = (f16*)(ws + 203423744);            // 4 MB
    f16* wgateH = (f16*)(ws + 207618048);            // 4 MB
    f16* imgH   = (f16*)(ws + 211812352);            // 4 MB region (1152 rows written)
    f16* imgTH  = (f16*)(ws + 216006656);            // 4 MB
    f16* imgW2T = (f16*)(ws + 220200960);            // 8 MB
    f16* capW1  = (f16*)(ws + 228589568);            // 4 MB
    float* w11Buf = (float*)(ws + 232783872);        // 4 KB
    float* score  = (float*)(ws + 232787968);        // 4 KB
    f16* qB = preLin;                                // alias (safe: per-element RAW in-thread)

    hipMemsetAsync(score, 0, C_ * I_ * sizeof(float), stream);
    convert_kernel<<<dim3(6272), dim3(256), 0, stream>>>(cap, w_lin, w_gate, img, capH, wlinH, wgateH, imgH);
    transpose_kernel<<<dim3(1024), dim3(256), 0, stream>>>(img, imgTH);
    w11_kernel<<<dim3(1024), dim3(64), 0, stream>>>(cap, w11Buf);
    imgw2t_kernel<<<dim3(16, 32), dim3(256), 0, stream>>>(wlinH, wgateH, imgH, imgW2T);
    qgemm_kernel<<<dim3(64), dim3(512), 0, stream>>>(capH, wlinH, wgateH, (const f16*)0, (const f16*)0,
                                                     b_lin, b_gate, capW1, lens, 0);
    // iter 0
    attn_kernel<<<dim3(1024), dim3(256), 0, stream>>>(imgH, imgTH, imgW2T, capH, (const f16*)0,
                                                      w11Buf, lens, preLin, preGate, score, 1, 1);
    combine_kernel<<<dim3(1024), dim3(256), 0, stream>>>(cap, capW1, preLin, preGate, b_lin, b_gate, qA, lens);
    // iter 1
    attn_kernel<<<dim3(1024), dim3(256), 0, stream>>>(imgH, imgTH, imgW2T, capH, qA,
                                                      w11Buf, lens, preLin, preGate, score, 0, 1);
    qgemm_kernel<<<dim3(2048), dim3(512), 0, stream>>>(qA, wlinH, wgateH, preLin, preGate,
                                                       b_lin, b_gate, qB, lens, 1);
    // iter 2 (q update dead; no pre, no wc stores)
    attn_kernel<<<dim3(1024), dim3(256), 0, stream>>>(imgH, imgTH, imgW2T, capH, qB,
                                                      w11Buf, lens, preLin, preGate, score, 0, 0);

    loss_kernel<<<dim3(1), dim3(64), 0, stream>>>(score, out);
}

// Round 6
// 620.949 us; speedup vs baseline: 19.4770x; 1.0353x over previous
//
#include <hip/hip_runtime.h>
#include <hip/hip_fp16.h>

#define C_ 32
#define I_ 32
#define W_ 32
#define R_ 36
#define D_ 1024
#define EPS_ 1e-8f
#define LAMBDA_ 9.0f
#define MARGIN_ 0.2f

typedef _Float16 f16;
typedef f16 half8 __attribute__((ext_vector_type(8)));
typedef f16 f16x4 __attribute__((ext_vector_type(4)));
typedef float f32x4 __attribute__((ext_vector_type(4)));

__device__ __forceinline__ void gload16(const void* g, void* l) {
    __builtin_amdgcn_global_load_lds((const __attribute__((address_space(1))) void*)g,
                                     (__attribute__((address_space(3))) void*)l, 16, 0, 0);
}

__device__ __forceinline__ f16x4 to_h4(f32x4 v) {
    f16x4 o; o[0] = (f16)v[0]; o[1] = (f16)v[1]; o[2] = (f16)v[2]; o[3] = (f16)v[3];
    return o;
}

// fp32 -> fp16 of cap, w_lin, w_gate, img (one float4 per thread)
__global__ __launch_bounds__(256) void convert_kernel(
    const float* __restrict__ cap, const float* __restrict__ wl, const float* __restrict__ wg,
    const float* __restrict__ img,
    f16* __restrict__ capH, f16* __restrict__ wlH, f16* __restrict__ wgH, f16* __restrict__ imgH)
{
    const int t = blockIdx.x * 256 + threadIdx.x;   // 1605632 total
    const float* src; f16* dst; int idx;
    if (t < 262144)        { src = cap; dst = capH; idx = t; }
    else if (t < 786432)   { src = wl;  dst = wlH;  idx = t - 262144; }
    else if (t < 1310720)  { src = wg;  dst = wgH;  idx = t - 786432; }
    else                   { src = img; dst = imgH; idx = t - 1310720; }
    float4 v = ((const float4*)src)[idx];
    f16x4 o; o[0] = (f16)v.x; o[1] = (f16)v.y; o[2] = (f16)v.z; o[3] = (f16)v.w;
    *(f16x4*)(dst + (size_t)idx * 4) = o;
}

// imgT (I, D, 64) fp16: imgT[i][d][r] = img[i][r][d], r>=36 zero.
__global__ __launch_bounds__(256) void transpose_kernel(
    const float* __restrict__ img, f16* __restrict__ imgTH)
{
    const int t = blockIdx.x * 256 + threadIdx.x;   // 262144 total
    const int i = t >> 13;
    const int g = (t >> 10) & 7;
    const int d = t & 1023;
    half8 o;
    #pragma unroll
    for (int j = 0; j < 8; j++) {
        const int r = g * 8 + j;
        o[j] = (r < 36) ? (f16)img[((size_t)i * 36 + r) * 1024 + d] : (f16)0.f;
    }
    *(half8*)(imgTH + (((size_t)i * 1024 + d) << 6) + g * 8) = o;
}

// w11Buf[c*32+w] = sum_d cap^2 (exact fp32)
__global__ __launch_bounds__(64) void w11_kernel(const float* __restrict__ cap,
                                                 float* __restrict__ w11Buf)
{
    const int row = blockIdx.x;
    const float* p = cap + (size_t)row * 1024;
    float s = 0.f;
    for (int e = threadIdx.x; e < 1024; e += 64) { float v = p[e]; s += v * v; }
    for (int off = 32; off > 0; off >>= 1) s += __shfl_down(s, off);
    if (threadIdx.x == 0) w11Buf[row] = s;
}

// imgW2T[i][j][r] = sum_d img[i][r][d] * Wpair2[j][d]  (j<1024: w_lin second-half
// cols, else w_gate). Layout (I, 2048, 64), r>=36 zeroed.
__global__ __launch_bounds__(256) void imgw2t_kernel(
    const f16* __restrict__ wlinH, const f16* __restrict__ wgateH,
    const f16* __restrict__ imgH, f16* __restrict__ imgW2T)
{
    const int jt = blockIdx.x;
    const int i  = blockIdx.y;
    __shared__ f16 sA[128 * 64];    // rows of 128B, chunk-swizzled
    __shared__ f16 sB[64 * 64];
    const int tid = threadIdx.x, lane = tid & 63, wv = tid >> 6;
    const int wm = wv >> 1, wn = wv & 1;
    f32x4 acc[4][2];
    #pragma unroll
    for (int a = 0; a < 4; a++) { acc[a][0] = (f32x4){0,0,0,0}; acc[a][1] = (f32x4){0,0,0,0}; }

    for (int ks = 0; ks < 16; ks++) {
        const int kk = ks * 64;
        __syncthreads();
        #pragma unroll
        for (int p = 0; p < 4; p++) {
            const int u = tid + p * 256;
            const int row = u >> 3, ch = u & 7;
            const int jr = jt * 128 + row;
            const f16* src = ((jr < 1024) ? (wlinH + (size_t)jr * 2048)
                                          : (wgateH + (size_t)(jr - 1024) * 2048))
                             + 1024 + kk + ((ch ^ (row & 7)) << 3);
            gload16(src, (char*)sA + u * 16);
        }
        #pragma unroll
        for (int p = 0; p < 2; p++) {
            const int u = tid + p * 256;
            const int row = u >> 3, ch = u & 7;
            const f16* src = imgH + (size_t)(i * 36 + row) * 1024 + kk + ((ch ^ (row & 7)) << 3);
            gload16(src, (char*)sB + u * 16);
        }
        __syncthreads();
        #pragma unroll
        for (int ksub = 0; ksub < 2; ksub++) {
            const int kch = (ksub << 2) | (lane >> 4);
            half8 af[4], bf[2];
            #pragma unroll
            for (int tm = 0; tm < 4; tm++) {
                const int row = wm * 64 + tm * 16 + (lane & 15);
                af[tm] = *(const half8*)((const char*)sA + row * 128 + ((kch ^ (row & 7)) << 4));
            }
            #pragma unroll
            for (int tn = 0; tn < 2; tn++) {
                const int row = wn * 32 + tn * 16 + (lane & 15);
                bf[tn] = *(const half8*)((const char*)sB + row * 128 + ((kch ^ (row & 7)) << 4));
            }
            #pragma unroll
            for (int tm = 0; tm < 4; tm++)
                #pragma unroll
                for (int tn = 0; tn < 2; tn++)
                    acc[tm][tn] = __builtin_amdgcn_mfma_f32_16x16x32_f16(af[tm], bf[tn], acc[tm][tn], 0, 0, 0);
        }
    }
    #pragma unroll
    for (int tm = 0; tm < 4; tm++)
        #pragma unroll
        for (int tn = 0; tn < 2; tn++)
            #pragma unroll
            for (int r = 0; r < 4; r++) {
                const int j = jt * 128 + wm * 64 + tm * 16 + (lane >> 4) * 4 + r;
                const int rc = wn * 32 + tn * 16 + (lane & 15);
                imgW2T[((size_t)i * 2048 + j) * 64 + rc] = (rc < 36) ? (f16)acc[tm][tn][r] : (f16)0.f;
            }
}

// One WG per (c,i), 4 waves. MFMA attn -> softmax -> MFMA phase-B.
// mode 0: iter0 (q=cap; fold qA = blend(cap, act(capW1+pre+b)) directly)
// mode 1: iter1 (q=qcur; store preLin/preGate)
// mode 2: iter2 (q=qcur; score only)
__global__ __launch_bounds__(256) void attn_kernel(
    const f16* __restrict__ imgH,       // (>=I*36 rows, D)
    const f16* __restrict__ imgTH,      // (I, D, 64)
    const f16* __restrict__ imgW2T,     // (I, 2048, 64)
    const f16* __restrict__ capH,       // (C, W, D)
    const f16* __restrict__ qcur,       // (C,W,I,D)
    const f16* __restrict__ capW1,      // (C*W, 2048)
    const float* __restrict__ capF,     // (C, W, D) fp32
    const float* __restrict__ b_lin, const float* __restrict__ b_gate,
    const float* __restrict__ w11Buf,
    const int* __restrict__ lens,
    f16* __restrict__ preLin,           // (C,W,I,1024)
    f16* __restrict__ preGate,          // (C,W,I,1024)
    f16* __restrict__ qOut,             // (C,W,I,D) [mode 0]
    float* __restrict__ score,          // (C, I)
    const int mode)
{
    __shared__ f16 sPA[2][10240];       // per buf: img[48][128] then q[32][128]
    __shared__ f16 sSmT[2048];          // smT [32][64], chunk-swizzled
    __shared__ float sAttn[36][33];
    __shared__ float sNrm[36];
    __shared__ float sW12[4][32];
    __shared__ float sW22[4][32];

    const int bid = blockIdx.x;
    const int c  = bid & 31;            // c fast: consecutive blocks share i
    const int i  = bid >> 5;
    const int len = lens[c];
    const int tid = threadIdx.x;
    const int lane = tid & 63;
    const int wv = tid >> 6;
    const int i36 = i * 36;
    const int iter0 = (mode == 0);

    const f16* qB = iter0 ? (const f16*)0 : (qcur + ((size_t)c * 1024 + i) * 1024);

    f32x4 accA[2] = {{0.f,0.f,0.f,0.f},{0.f,0.f,0.f,0.f}};

    auto stageA = [&](int b, int k0) {
        for (int g = wv; g < 20; g += 4) {
            f16* dst; const f16* src;
            if (g < 12) {
                const int row = g * 4 + (lane >> 4);
                dst = &sPA[b][g * 512];
                src = imgH + (size_t)(i36 + row) * 1024 + k0 + (((lane & 15) ^ (row & 7)) << 3);
            } else {
                const int w = (g - 12) * 4 + (lane >> 4);
                dst = &sPA[b][6144 + (g - 12) * 512];
                src = (iter0 ? (capH + (size_t)(c * 32 + w) * 1024)
                             : (qB + (size_t)w * (32 * 1024)))
                      + k0 + (((lane & 15) ^ (w & 7)) << 3);
            }
            gload16(src, dst);
        }
    };

    stageA(0, 0);
    __syncthreads();
    int cur = 0;
    for (int kc = 0; kc < 8; kc++) {
        if (kc < 7) stageA(cur ^ 1, (kc + 1) * 128);
        if (wv < 3) {
            #pragma unroll
            for (int ks = 0; ks < 4; ks++) {
                const int arow = wv * 16 + (lane & 15);
                const half8 af = *(const half8*)&sPA[cur][arow * 128 + ((((ks << 2) | (lane >> 4)) ^ (arow & 7)) << 3)];
                #pragma unroll
                for (int nt = 0; nt < 2; nt++) {
                    const int brow = nt * 16 + (lane & 15);
                    const half8 bf = *(const half8*)&sPA[cur][6144 + brow * 128 + ((((ks << 2) | (lane >> 4)) ^ (brow & 7)) << 3)];
                    accA[nt] = __builtin_amdgcn_mfma_f32_16x16x32_f16(af, bf, accA[nt], 0, 0, 0);
                }
            }
        }
        __syncthreads();
        cur ^= 1;
    }

    if (wv < 3) {
        #pragma unroll
        for (int nt = 0; nt < 2; nt++) {
            #pragma unroll
            for (int r = 0; r < 4; r++) {
                const int rr = wv * 16 + (lane >> 4) * 4 + r;
                if (rr < 36) {
                    float v = accA[nt][r];
                    sAttn[rr][nt * 16 + (lane & 15)] = (v >= 0.f) ? v : 0.1f * v;
                }
            }
        }
    }
    __syncthreads();

    if (tid < 36) {
        float s = 0.f;
        for (int w = 0; w < len; w++) { float v = sAttn[tid][w]; s += v * v; }
        sNrm[tid] = sqrtf(s) + EPS_;
    }
    __syncthreads();

    if (tid < 32) {
        if (tid < len) {
            float vals[36]; float m = -1e30f;
            #pragma unroll
            for (int r = 0; r < 36; r++) {
                float v = (sAttn[r][tid] / sNrm[r]) * LAMBDA_;
                vals[r] = v; m = fmaxf(m, v);
            }
            float sum = 0.f;
            #pragma unroll
            for (int r = 0; r < 36; r++) { float e = __expf(vals[r] - m); sum += e; vals[r] = e; }
            const float inv = 1.0f / sum;
            #pragma unroll
            for (int r = 0; r < 64; r++) {
                const int off = tid * 64 + ((((r >> 3) ^ (tid & 7)) << 3) | (r & 7));
                sSmT[off] = (r < 36) ? (f16)(vals[r] * inv) : (f16)0.f;
            }
        } else {
            #pragma unroll
            for (int r = 0; r < 64; r++) sSmT[tid * 64 + r] = (f16)0.f;
        }
    }
    __syncthreads();

    // sm-row frags (row/col = w = lane&15, k-chunk = (lane>>4)*8) — used as the
    // B-operand of all phase-B MFMAs so the contiguous dim lands in the reg quad.
    half8 af[2][2];
    #pragma unroll
    for (int mt = 0; mt < 2; mt++)
        #pragma unroll
        for (int ks = 0; ks < 2; ks++) {
            const int row = mt * 16 + (lane & 15);
            af[mt][ks] = *(const half8*)&sSmT[row * 64 + ((((ks << 2) | (lane >> 4)) ^ (row & 7)) << 3)];
        }

    // ---- wc part: acc = mfma(imgT_dRows, smFrag) -> lane: w=mt*16+(lane&15),
    // d-quad = dt*16+(lane>>4)*4.  cos sums accumulate per lane.
    float w12L[2] = {0.f, 0.f}, w22L[2] = {0.f, 0.f};
    const f16* imgTbase = imgTH + (((size_t)i) << 16);
    for (int t = 0; t < 16; t++) {
        const int dt = t * 4 + wv;                   // 0..63
        const int dA = dt * 16 + (lane & 15);
        const half8 bf0 = *(const half8*)(imgTbase + ((size_t)dA << 6) + ((lane >> 4) << 3));
        const half8 bf1 = *(const half8*)(imgTbase + ((size_t)dA << 6) + 32 + ((lane >> 4) << 3));
        const int d0 = dt * 16 + (lane >> 4) * 4;
        #pragma unroll
        for (int mt = 0; mt < 2; mt++) {
            f32x4 acc = {0.f, 0.f, 0.f, 0.f};
            acc = __builtin_amdgcn_mfma_f32_16x16x32_f16(bf0, af[mt][0], acc, 0, 0, 0);
            acc = __builtin_amdgcn_mfma_f32_16x16x32_f16(bf1, af[mt][1], acc, 0, 0, 0);
            const int w = mt * 16 + (lane & 15);
            const f16x4 cp = *(const f16x4*)(capH + (size_t)(c * 32 + w) * 1024 + d0);
            #pragma unroll
            for (int r = 0; r < 4; r++) {
                const float v = acc[r];
                w12L[mt] += (float)cp[r] * v;
                w22L[mt] += v * v;
            }
        }
    }

    // ---- pre / qA part
    if (mode == 1) {
        const f16* w2base = imgW2T + (((size_t)i * 2048) << 6);
        for (int t = 0; t < 32; t++) {
            const int jt_ = t * 4 + wv;              // 0..127
            const int jA = jt_ * 16 + (lane & 15);
            const f16* bb = w2base + ((size_t)jA << 6);
            const half8 bf0 = *(const half8*)(bb + ((lane >> 4) << 3));
            const half8 bf1 = *(const half8*)(bb + 32 + ((lane >> 4) << 3));
            f16* dstBase = (jt_ < 64) ? preLin : preGate;
            const int jl = ((jt_ * 16) & 1023) + (lane >> 4) * 4;
            #pragma unroll
            for (int mt = 0; mt < 2; mt++) {
                f32x4 acc = {0.f, 0.f, 0.f, 0.f};
                acc = __builtin_amdgcn_mfma_f32_16x16x32_f16(bf0, af[mt][0], acc, 0, 0, 0);
                acc = __builtin_amdgcn_mfma_f32_16x16x32_f16(bf1, af[mt][1], acc, 0, 0, 0);
                const int w = mt * 16 + (lane & 15);
                if (w < len)
                    *(f16x4*)(dstBase + (((size_t)((c * 32 + w) * 32 + i)) << 10) + jl) = to_h4(acc);
            }
        }
    } else if (mode == 0) {
        const f16* w2base = imgW2T + (((size_t)i * 2048) << 6);
        for (int t = 0; t < 16; t++) {
            const int jt_ = t * 4 + wv;              // 0..63
            const int jA = jt_ * 16 + (lane & 15);
            const half8 bL0 = *(const half8*)(w2base + ((size_t)jA << 6) + ((lane >> 4) << 3));
            const half8 bL1 = *(const half8*)(w2base + ((size_t)jA << 6) + 32 + ((lane >> 4) << 3));
            const half8 bG0 = *(const half8*)(w2base + ((size_t)(1024 + jA) << 6) + ((lane >> 4) << 3));
            const half8 bG1 = *(const half8*)(w2base + ((size_t)(1024 + jA) << 6) + 32 + ((lane >> 4) << 3));
            const int j = jt_ * 16 + (lane >> 4) * 4;
            #pragma unroll
            for (int mt = 0; mt < 2; mt++) {
                f32x4 aL = {0.f, 0.f, 0.f, 0.f}, aG = {0.f, 0.f, 0.f, 0.f};
                aL = __builtin_amdgcn_mfma_f32_16x16x32_f16(bL0, af[mt][0], aL, 0, 0, 0);
                aL = __builtin_amdgcn_mfma_f32_16x16x32_f16(bL1, af[mt][1], aL, 0, 0, 0);
                aG = __builtin_amdgcn_mfma_f32_16x16x32_f16(bG0, af[mt][0], aG, 0, 0, 0);
                aG = __builtin_amdgcn_mfma_f32_16x16x32_f16(bG1, af[mt][1], aG, 0, 0, 0);
                const int w = mt * 16 + (lane & 15);
                if (w < len) {
                    const size_t cw = (size_t)(c * 32 + w);
                    const f16x4 c1L = *(const f16x4*)(capW1 + cw * 2048 + j);
                    const f16x4 c1G = *(const f16x4*)(capW1 + cw * 2048 + 1024 + j);
                    const f32x4 bl = *(const f32x4*)(b_lin + j);
                    const f32x4 bg = *(const f32x4*)(b_gate + j);
                    const f32x4 cp = *(const f32x4*)(capF + cw * 1024 + j);
                    f16x4 o;
                    #pragma unroll
                    for (int r = 0; r < 4; r++) {
                        const float h = tanhf(aL[r] + (float)c1L[r] + bl[r]);
                        const float g = 1.f / (1.f + __expf(-(aG[r] + (float)c1G[r] + bg[r])));
                        o[r] = (f16)(cp[r] * g + h * (1.f - g));
                    }
                    *(f16x4*)(qOut + ((cw * 32 + i) << 10) + j) = o;
                }
            }
        }
    }

    // ---- cos reduce: xor over lane>>4 groups, spill per-wave, final combine
    #pragma unroll
    for (int mask = 16; mask <= 32; mask <<= 1) {
        #pragma unroll
        for (int mt = 0; mt < 2; mt++) {
            w12L[mt] += __shfl_xor(w12L[mt], mask);
            w22L[mt] += __shfl_xor(w22L[mt], mask);
        }
    }
    if (lane < 16) {
        #pragma unroll
        for (int mt = 0; mt < 2; mt++) {
            sW12[wv][mt * 16 + lane] = w12L[mt];
            sW22[wv][mt * 16 + lane] = w22L[mt];
        }
    }
    __syncthreads();
    if (tid < 32) {
        const int w = tid;
        float part = 0.f;
        if (w < len) {
            const float a = sW12[0][w] + sW12[1][w] + sW12[2][w] + sW12[3][w];
            const float b = sW22[0][w] + sW22[1][w] + sW22[2][w] + sW22[3][w];
            part = a / fmaxf(sqrtf(w11Buf[c * 32 + w]) * sqrtf(b), EPS_);
        }
        for (int off = 16; off > 0; off >>= 1) part += __shfl_down(part, off);
        if (tid == 0) score[c * 32 + i] += part / (float)len;
    }
}

// q-half GEMM, operand-swapped (weights = A operand -> j contiguous per lane).
// mode0: capW1 = capH @ W1pair^T (M=1024). mode1: qnext = blend(...) (M=32768).
// BM=128 m, B rows = 64 j x {lin,gate}, BK=32, dbuf 1-barrier, 4 waves.
__global__ __launch_bounds__(256, 4) void qgemm_kernel(
    const f16* __restrict__ Aptr,
    const f16* __restrict__ wlinH, const f16* __restrict__ wgateH,
    const f16* __restrict__ preLin, const f16* __restrict__ preGate,
    const float* __restrict__ b_lin, const float* __restrict__ b_gate,
    f16* __restrict__ outp,
    const int* __restrict__ lens, const int mode)
{
    const int bid = blockIdx.x;
    const int jt = bid & 15;                // 16 j-tiles of 64
    const int cm = bid >> 4;
    int len = 32;
    if (mode) { len = lens[cm >> 3]; if ((cm & 7) * 4 >= len) return; }
    const int m0 = cm * 128;

    __shared__ char sMem[32768];            // 2 bufs x (A 8K | B 8K)

    const int tid = threadIdx.x;
    const int lane = tid & 63;
    const int wv = tid >> 6;                // m-quarter

    auto stage = [&](int b, int ks) {
        const int kk = ks * 32;
        char* base = sMem + b * 16384;
        #pragma unroll
        for (int p = 0; p < 2; p++) {
            const int u = tid + p * 256;
            const int row = u >> 2, kg = u & 3;
            const f16* src = Aptr + (size_t)(m0 + row) * 1024 + kk + ((kg ^ ((row >> 1) & 3)) << 3);
            gload16(src, base + u * 16);
        }
        #pragma unroll
        for (int p = 0; p < 2; p++) {
            const int u = tid + p * 256;
            const int row = u >> 2, kg = u & 3;
            const int j = jt * 64 + (row & 63);
            const f16* wsrc = ((row < 64) ? wlinH : wgateH) + (size_t)j * 2048 + kk + ((kg ^ ((row >> 1) & 3)) << 3);
            gload16(wsrc, base + 8192 + u * 16);
        }
    };

    f32x4 acc[8][2];
    #pragma unroll
    for (int a = 0; a < 8; a++) { acc[a][0] = (f32x4){0,0,0,0}; acc[a][1] = (f32x4){0,0,0,0}; }

    stage(0, 0);
    __syncthreads();
    int cur = 0;
    for (int ks = 0; ks < 32; ks++) {
        if (ks < 31) stage(cur ^ 1, ks + 1);
        const char* cb = sMem + cur * 16384;
        half8 bq[2];
        #pragma unroll
        for (int mt = 0; mt < 2; mt++) {
            const int m = wv * 32 + mt * 16 + (lane & 15);
            bq[mt] = *(const half8*)(cb + m * 64 + ((((lane >> 4) ^ ((m >> 1) & 3))) << 4));
        }
        __builtin_amdgcn_s_setprio(1);
        #pragma unroll
        for (int half = 0; half < 2; half++) {
            half8 aw[4];
            #pragma unroll
            for (int q = 0; q < 4; q++) {
                const int rw = (half * 4 + q) * 16 + (lane & 15);
                aw[q] = *(const half8*)(cb + 8192 + rw * 64 + ((((lane >> 4) ^ ((rw >> 1) & 3))) << 4));
            }
            #pragma unroll
            for (int q = 0; q < 4; q++)
                #pragma unroll
                for (int mt = 0; mt < 2; mt++)
                    acc[half * 4 + q][mt] = __builtin_amdgcn_mfma_f32_16x16x32_f16(aw[q], bq[mt], acc[half * 4 + q][mt], 0, 0, 0);
        }
        __builtin_amdgcn_s_setprio(0);
        __syncthreads();
        cur ^= 1;
    }

    // epilogue: lane holds fixed m, contiguous j-quads
    #pragma unroll
    for (int mt = 0; mt < 2; mt++) {
        const int gm = m0 + wv * 32 + mt * 16 + (lane & 15);
        bool active = true;
        if (mode) active = (((gm >> 5) & 31) < len);
        #pragma unroll
        for (int jt8 = 0; jt8 < 4; jt8++) {
            const int jl = jt8 * 16 + (lane >> 4) * 4;
            const int j = jt * 64 + jl;
            const f32x4 aL = acc[jt8][mt];
            const f32x4 aG = acc[jt8 + 4][mt];
            if (mode == 0) {
                *(f16x4*)(outp + (size_t)gm * 2048 + j) = to_h4(aL);
                *(f16x4*)(outp + (size_t)gm * 2048 + 1024 + j) = to_h4(aG);
            } else if (active) {
                const size_t off = ((size_t)gm << 10) + j;
                const f16x4 pl = *(const f16x4*)(preLin + off);
                const f16x4 pg = *(const f16x4*)(preGate + off);
                const f16x4 qo = *(const f16x4*)(Aptr + off);
                const f32x4 bl = *(const f32x4*)(b_lin + j);
                const f32x4 bg = *(const f32x4*)(b_gate + j);
                f16x4 o;
                #pragma unroll
                for (int r = 0; r < 4; r++) {
                    const float h = tanhf(aL[r] + (float)pl[r] + bl[r]);
                    const float g = 1.f / (1.f + __expf(-(aG[r] + (float)pg[r] + bg[r])));
                    o[r] = (f16)((float)qo[r] * g + h * (1.f - g));
                }
                *(f16x4*)(outp + off) = o;
            }
        }
    }
}

__global__ __launch_bounds__(64) void loss_kernel(const float* __restrict__ score,
                                                  float* __restrict__ out)
{
    __shared__ float s[32][33];
    __shared__ float diag[32];
    const int tid = threadIdx.x;
    for (int idx = tid; idx < 1024; idx += 64) s[idx >> 5][idx & 31] = score[idx];
    __syncthreads();
    if (tid < 32) diag[tid] = s[tid][tid];
    __syncthreads();
    float total = 0.f;
    if (tid < 32) {
        float m1 = 0.f, m2 = 0.f;
        for (int k = 0; k < 32; k++) {
            if (k != tid) {
                m1 = fmaxf(m1, fmaxf(0.f, MARGIN_ + s[tid][k] - diag[tid]));
                m2 = fmaxf(m2, fmaxf(0.f, MARGIN_ + s[k][tid] - diag[tid]));
            }
        }
        total = m1 + m2;
    }
    for (int off = 32; off > 0; off >>= 1) total += __shfl_down(total, off);
    if (tid == 0) out[0] = total;
}

extern "C" void kernel_launch(void* const* d_in, const int* in_sizes, int n_in,
                              void* d_out, int out_size, void* d_ws, size_t ws_size,
                              hipStream_t stream) {
    const float* img    = (const float*)d_in[0];
    const float* cap    = (const float*)d_in[1];
    const int*   lens   = (const int*)d_in[2];
    const float* w_lin  = (const float*)d_in[3];
    const float* b_lin  = (const float*)d_in[4];
    const float* w_gate = (const float*)d_in[5];
    const float* b_gate = (const float*)d_in[6];
    float* out = (float*)d_out;

    char* ws = (char*)d_ws;
    f16* qA     = (f16*)(ws);                        // 64 MB
    f16* preLin = (f16*)(ws + 67108864);             // 64 MB (qB aliases here)
    f16* preGate= (f16*)(ws + 134217728);            // 64 MB
    f16* capH   = (f16*)(ws + 201326592);            // 2 MB
    f16* wlinH  = (f16*)(ws + 203423744);            // 4 MB
    f16* wgateH = (f16*)(ws + 207618048);            // 4 MB
    f16* imgH   = (f16*)(ws + 211812352);            // 4 MB region (1152 rows used)
    f16* imgTH  = (f16*)(ws + 216006656);            // 4 MB
    f16* imgW2T = (f16*)(ws + 220200960);            // 8 MB
    f16* capW1  = (f16*)(ws + 228589568);            // 4 MB
    float* w11Buf = (float*)(ws + 232783872);        // 4 KB
    float* score  = (float*)(ws + 232787968);        // 4 KB
    f16* qB = preLin;                                // alias (per-element RAW in-thread)

    hipMemsetAsync(score, 0, C_ * I_ * sizeof(float), stream);
    convert_kernel<<<dim3(6272), dim3(256), 0, stream>>>(cap, w_lin, w_gate, img, capH, wlinH, wgateH, imgH);
    transpose_kernel<<<dim3(1024), dim3(256), 0, stream>>>(img, imgTH);
    w11_kernel<<<dim3(1024), dim3(64), 0, stream>>>(cap, w11Buf);
    imgw2t_kernel<<<dim3(16, 32), dim3(256), 0, stream>>>(wlinH, wgateH, imgH, imgW2T);
    qgemm_kernel<<<dim3(128), dim3(256), 0, stream>>>(capH, wlinH, wgateH, (const f16*)0, (const f16*)0,
                                                      b_lin, b_gate, capW1, lens, 0);
    // iter 0: attn + fused qA blend (no pre materialization, no combine kernel)
    attn_kernel<<<dim3(1024), dim3(256), 0, stream>>>(imgH, imgTH, imgW2T, capH, (const f16*)0,
                                                      capW1, cap, b_lin, b_gate, w11Buf, lens,
                                                      preLin, preGate, qA, score, 0);
    // iter 1: attn + pre stores
    attn_kernel<<<dim3(1024), dim3(256), 0, stream>>>(imgH, imgTH, imgW2T, capH, qA,
                                                      capW1, cap, b_lin, b_gate, w11Buf, lens,
                                                      preLin, preGate, (f16*)0, score, 1);
    qgemm_kernel<<<dim3(4096), dim3(256), 0, stream>>>(qA, wlinH, wgateH, preLin, preGate,
                                                       b_lin, b_gate, qB, lens, 1);
    // iter 2: score only
    attn_kernel<<<dim3(1024), dim3(256), 0, stream>>>(imgH, imgTH, imgW2T, capH, qB,
                                                      capW1, cap, b_lin, b_gate, w11Buf, lens,
                                                      preLin, preGate, (f16*)0, score, 2);

    loss_kernel<<<dim3(1), dim3(64), 0, stream>>>(score, out);
}

// Round 7
// 591.205 us; speedup vs baseline: 20.4569x; 1.0503x over previous
//
#include <hip/hip_runtime.h>
#include <hip/hip_fp16.h>

#define C_ 32
#define I_ 32
#define W_ 32
#define R_ 36
#define D_ 1024
#define EPS_ 1e-8f
#define LAMBDA_ 9.0f
#define MARGIN_ 0.2f

typedef _Float16 f16;
typedef f16 half8 __attribute__((ext_vector_type(8)));
typedef f16 f16x4 __attribute__((ext_vector_type(4)));
typedef float f32x4 __attribute__((ext_vector_type(4)));

__device__ __forceinline__ void gload16(const void* g, void* l) {
    __builtin_amdgcn_global_load_lds((const __attribute__((address_space(1))) void*)g,
                                     (__attribute__((address_space(3))) void*)l, 16, 0, 0);
}

__device__ __forceinline__ f16x4 to_h4(f32x4 v) {
    f16x4 o; o[0] = (f16)v[0]; o[1] = (f16)v[1]; o[2] = (f16)v[2]; o[3] = (f16)v[3];
    return o;
}

// fp32 -> fp16 of cap, w_lin, w_gate, img (one float4 per thread)
__global__ __launch_bounds__(256) void convert_kernel(
    const float* __restrict__ cap, const float* __restrict__ wl, const float* __restrict__ wg,
    const float* __restrict__ img,
    f16* __restrict__ capH, f16* __restrict__ wlH, f16* __restrict__ wgH, f16* __restrict__ imgH)
{
    const int t = blockIdx.x * 256 + threadIdx.x;   // 1605632 total
    const float* src; f16* dst; int idx;
    if (t < 262144)        { src = cap; dst = capH; idx = t; }
    else if (t < 786432)   { src = wl;  dst = wlH;  idx = t - 262144; }
    else if (t < 1310720)  { src = wg;  dst = wgH;  idx = t - 786432; }
    else                   { src = img; dst = imgH; idx = t - 1310720; }
    float4 v = ((const float4*)src)[idx];
    f16x4 o; o[0] = (f16)v.x; o[1] = (f16)v.y; o[2] = (f16)v.z; o[3] = (f16)v.w;
    *(f16x4*)(dst + (size_t)idx * 4) = o;
}

// imgT (I, D, 64) fp16: imgT[i][d][r] = img[i][r][d], r>=36 zero.
__global__ __launch_bounds__(256) void transpose_kernel(
    const float* __restrict__ img, f16* __restrict__ imgTH)
{
    const int t = blockIdx.x * 256 + threadIdx.x;   // 262144 total
    const int i = t >> 13;
    const int g = (t >> 10) & 7;
    const int d = t & 1023;
    half8 o;
    #pragma unroll
    for (int j = 0; j < 8; j++) {
        const int r = g * 8 + j;
        o[j] = (r < 36) ? (f16)img[((size_t)i * 36 + r) * 1024 + d] : (f16)0.f;
    }
    *(half8*)(imgTH + (((size_t)i * 1024 + d) << 6) + g * 8) = o;
}

// w11Buf[c*32+w] = sum_d cap^2 (exact fp32)
__global__ __launch_bounds__(64) void w11_kernel(const float* __restrict__ cap,
                                                 float* __restrict__ w11Buf)
{
    const int row = blockIdx.x;
    const float* p = cap + (size_t)row * 1024;
    float s = 0.f;
    for (int e = threadIdx.x; e < 1024; e += 64) { float v = p[e]; s += v * v; }
    for (int off = 32; off > 0; off >>= 1) s += __shfl_down(s, off);
    if (threadIdx.x == 0) w11Buf[row] = s;
}

// imgW2T[i][j][r] = sum_d img[i][r][d] * Wpair2[j][d]  (j<1024: w_lin second-half
// cols, else w_gate). Layout (I, 2048, 64), r>=36 zeroed.
__global__ __launch_bounds__(256) void imgw2t_kernel(
    const f16* __restrict__ wlinH, const f16* __restrict__ wgateH,
    const f16* __restrict__ imgH, f16* __restrict__ imgW2T)
{
    const int jt = blockIdx.x;
    const int i  = blockIdx.y;
    __shared__ f16 sA[128 * 64];    // rows of 128B, chunk-swizzled
    __shared__ f16 sB[64 * 64];
    const int tid = threadIdx.x, lane = tid & 63, wv = tid >> 6;
    const int wm = wv >> 1, wn = wv & 1;
    f32x4 acc[4][2];
    #pragma unroll
    for (int a = 0; a < 4; a++) { acc[a][0] = (f32x4){0,0,0,0}; acc[a][1] = (f32x4){0,0,0,0}; }

    for (int ks = 0; ks < 16; ks++) {
        const int kk = ks * 64;
        __syncthreads();
        #pragma unroll
        for (int p = 0; p < 4; p++) {
            const int u = tid + p * 256;
            const int row = u >> 3, ch = u & 7;
            const int jr = jt * 128 + row;
            const f16* src = ((jr < 1024) ? (wlinH + (size_t)jr * 2048)
                                          : (wgateH + (size_t)(jr - 1024) * 2048))
                             + 1024 + kk + ((ch ^ (row & 7)) << 3);
            gload16(src, (char*)sA + u * 16);
        }
        #pragma unroll
        for (int p = 0; p < 2; p++) {
            const int u = tid + p * 256;
            const int row = u >> 3, ch = u & 7;
            const f16* src = imgH + (size_t)(i * 36 + row) * 1024 + kk + ((ch ^ (row & 7)) << 3);
            gload16(src, (char*)sB + u * 16);
        }
        __syncthreads();
        #pragma unroll
        for (int ksub = 0; ksub < 2; ksub++) {
            const int kch = (ksub << 2) | (lane >> 4);
            half8 af[4], bf[2];
            #pragma unroll
            for (int tm = 0; tm < 4; tm++) {
                const int row = wm * 64 + tm * 16 + (lane & 15);
                af[tm] = *(const half8*)((const char*)sA + row * 128 + ((kch ^ (row & 7)) << 4));
            }
            #pragma unroll
            for (int tn = 0; tn < 2; tn++) {
                const int row = wn * 32 + tn * 16 + (lane & 15);
                bf[tn] = *(const half8*)((const char*)sB + row * 128 + ((kch ^ (row & 7)) << 4));
            }
            #pragma unroll
            for (int tm = 0; tm < 4; tm++)
                #pragma unroll
                for (int tn = 0; tn < 2; tn++)
                    acc[tm][tn] = __builtin_amdgcn_mfma_f32_16x16x32_f16(af[tm], bf[tn], acc[tm][tn], 0, 0, 0);
        }
    }
    #pragma unroll
    for (int tm = 0; tm < 4; tm++)
        #pragma unroll
        for (int tn = 0; tn < 2; tn++)
            #pragma unroll
            for (int r = 0; r < 4; r++) {
                const int j = jt * 128 + wm * 64 + tm * 16 + (lane >> 4) * 4 + r;
                const int rc = wn * 32 + tn * 16 + (lane & 15);
                imgW2T[((size_t)i * 2048 + j) * 64 + rc] = (rc < 36) ? (f16)acc[tm][tn][r] : (f16)0.f;
            }
}

// One WG per (c,i), 4 waves. MFMA attn -> softmax -> MFMA phase-B.
// MODE 0: iter0 (q=cap; fused qOut = blend(cap, act(capW1+pre+b)))
// MODE 1: iter1 (q=qcur; store preLin/preGate)
// MODE 2: iter2 (q=qcur; score only)
template<int MODE>
__global__ __launch_bounds__(256, 3) void attn_kernel(
    const f16* __restrict__ imgH,       // (>=I*36 rows, D)
    const f16* __restrict__ imgTH,      // (I, D, 64)
    const f16* __restrict__ imgW2T,     // (I, 2048, 64)
    const f16* __restrict__ capH,       // (C, W, D)
    const f16* __restrict__ qcur,       // (C,W,I,D)
    const f16* __restrict__ capW1,      // (C*W, 2048)
    const float* __restrict__ b_lin, const float* __restrict__ b_gate,
    const float* __restrict__ w11Buf,
    const int* __restrict__ lens,
    f16* __restrict__ preLin,           // (C,W,I,1024)
    f16* __restrict__ preGate,          // (C,W,I,1024)
    f16* __restrict__ qOut,             // (C,W,I,D) [MODE 0]
    float* __restrict__ score)          // (C, I)
{
    __shared__ f16 sPA[2][10240];       // per buf: img[48][128] then q[32][128]
    __shared__ f16 sSmT[2048];          // smT [32][64], chunk-swizzled
    __shared__ float sAttn[36][33];
    __shared__ float sNrm[36];          // holds LAMBDA / (||row|| + eps)
    __shared__ float sW12[4][32];
    __shared__ float sW22[4][32];

    // XCD-aware: same-i blocks colocate on one XCD (bid%8 fixes i-group)
    const int bid = blockIdx.x;
    const int c  = bid >> 5;
    const int i  = ((bid & 7) << 2) | ((bid >> 3) & 3);
    const int len = lens[c];
    const int tid = threadIdx.x;
    const int lane = tid & 63;
    const int wv = tid >> 6;
    const int i36 = i * 36;

    const f16* qB = (MODE == 0) ? (const f16*)0 : (qcur + ((size_t)c * 1024 + i) * 1024);

    f32x4 accA[2] = {{0.f,0.f,0.f,0.f},{0.f,0.f,0.f,0.f}};

    auto stageA = [&](int b, int k0) {
        for (int g = wv; g < 20; g += 4) {
            f16* dst; const f16* src;
            if (g < 12) {
                const int row = g * 4 + (lane >> 4);
                dst = &sPA[b][g * 512];
                src = imgH + (size_t)(i36 + row) * 1024 + k0 + (((lane & 15) ^ (row & 7)) << 3);
            } else {
                const int w = (g - 12) * 4 + (lane >> 4);
                dst = &sPA[b][6144 + (g - 12) * 512];
                src = ((MODE == 0) ? (capH + (size_t)(c * 32 + w) * 1024)
                                   : (qB + (size_t)w * (32 * 1024)))
                      + k0 + (((lane & 15) ^ (w & 7)) << 3);
            }
            gload16(src, dst);
        }
    };

    stageA(0, 0);
    __syncthreads();
    int cur = 0;
    for (int kc = 0; kc < 8; kc++) {
        if (kc < 7) stageA(cur ^ 1, (kc + 1) * 128);
        if (wv < 3) {
            #pragma unroll
            for (int ks = 0; ks < 4; ks++) {
                const int arow = wv * 16 + (lane & 15);
                const half8 af = *(const half8*)&sPA[cur][arow * 128 + ((((ks << 2) | (lane >> 4)) ^ (arow & 7)) << 3)];
                #pragma unroll
                for (int nt = 0; nt < 2; nt++) {
                    const int brow = nt * 16 + (lane & 15);
                    const half8 bf = *(const half8*)&sPA[cur][6144 + brow * 128 + ((((ks << 2) | (lane >> 4)) ^ (brow & 7)) << 3)];
                    accA[nt] = __builtin_amdgcn_mfma_f32_16x16x32_f16(af, bf, accA[nt], 0, 0, 0);
                }
            }
        }
        __syncthreads();
        cur ^= 1;
    }

    if (wv < 3) {
        #pragma unroll
        for (int nt = 0; nt < 2; nt++) {
            #pragma unroll
            for (int r = 0; r < 4; r++) {
                const int rr = wv * 16 + (lane >> 4) * 4 + r;
                if (rr < 36) {
                    float v = accA[nt][r];
                    sAttn[rr][nt * 16 + (lane & 15)] = (v >= 0.f) ? v : 0.1f * v;
                }
            }
        }
    }
    __syncthreads();

    if (tid < 36) {
        float s = 0.f;
        for (int w = 0; w < len; w++) { float v = sAttn[tid][w]; s += v * v; }
        sNrm[tid] = LAMBDA_ / (sqrtf(s) + EPS_);
    }
    __syncthreads();

    // 3-pass softmax over r (re-reads LDS instead of a vals[36] register array)
    if (tid < 32) {
        if (tid < len) {
            float m = -1e30f;
            #pragma unroll
            for (int r = 0; r < 36; r++) m = fmaxf(m, sAttn[r][tid] * sNrm[r]);
            float sum = 0.f;
            #pragma unroll
            for (int r = 0; r < 36; r++) sum += __expf(sAttn[r][tid] * sNrm[r] - m);
            const float inv = 1.0f / sum;
            #pragma unroll
            for (int r = 0; r < 64; r++) {
                const int off = tid * 64 + ((((r >> 3) ^ (tid & 7)) << 3) | (r & 7));
                sSmT[off] = (r < 36) ? (f16)(__expf(sAttn[r][tid] * sNrm[r] - m) * inv) : (f16)0.f;
            }
        } else {
            #pragma unroll
            for (int r = 0; r < 64; r++) sSmT[tid * 64 + r] = (f16)0.f;
        }
    }
    __syncthreads();

    // sm-row frags used as B-operand of phase-B MFMAs (contiguous dim -> reg quad)
    half8 af[2][2];
    #pragma unroll
    for (int mt = 0; mt < 2; mt++)
        #pragma unroll
        for (int ks = 0; ks < 2; ks++) {
            const int row = mt * 16 + (lane & 15);
            af[mt][ks] = *(const half8*)&sSmT[row * 64 + ((((ks << 2) | (lane >> 4)) ^ (row & 7)) << 3)];
        }

    // ---- wc part: lane: w = mt*16+(lane&15), d-quad = dt*16+(lane>>4)*4
    float w12L[2] = {0.f, 0.f}, w22L[2] = {0.f, 0.f};
    const f16* imgTbase = imgTH + (((size_t)i) << 16);
    for (int t = 0; t < 16; t++) {
        const int dt = t * 4 + wv;                   // 0..63
        const int dA = dt * 16 + (lane & 15);
        const half8 bf0 = *(const half8*)(imgTbase + ((size_t)dA << 6) + ((lane >> 4) << 3));
        const half8 bf1 = *(const half8*)(imgTbase + ((size_t)dA << 6) + 32 + ((lane >> 4) << 3));
        const int d0 = dt * 16 + (lane >> 4) * 4;
        #pragma unroll
        for (int mt = 0; mt < 2; mt++) {
            f32x4 acc = {0.f, 0.f, 0.f, 0.f};
            acc = __builtin_amdgcn_mfma_f32_16x16x32_f16(bf0, af[mt][0], acc, 0, 0, 0);
            acc = __builtin_amdgcn_mfma_f32_16x16x32_f16(bf1, af[mt][1], acc, 0, 0, 0);
            const int w = mt * 16 + (lane & 15);
            const f16x4 cp = *(const f16x4*)(capH + (size_t)(c * 32 + w) * 1024 + d0);
            #pragma unroll
            for (int r = 0; r < 4; r++) {
                const float v = acc[r];
                w12L[mt] += (float)cp[r] * v;
                w22L[mt] += v * v;
            }
        }
    }

    // ---- pre / qOut part
    if (MODE == 1) {
        const f16* w2base = imgW2T + (((size_t)i * 2048) << 6);
        for (int t = 0; t < 32; t++) {
            const int jt_ = t * 4 + wv;              // 0..127
            const int jA = jt_ * 16 + (lane & 15);
            const f16* bb = w2base + ((size_t)jA << 6);
            const half8 bf0 = *(const half8*)(bb + ((lane >> 4) << 3));
            const half8 bf1 = *(const half8*)(bb + 32 + ((lane >> 4) << 3));
            f16* dstBase = (jt_ < 64) ? preLin : preGate;
            const int jl = ((jt_ * 16) & 1023) + (lane >> 4) * 4;
            #pragma unroll
            for (int mt = 0; mt < 2; mt++) {
                f32x4 acc = {0.f, 0.f, 0.f, 0.f};
                acc = __builtin_amdgcn_mfma_f32_16x16x32_f16(bf0, af[mt][0], acc, 0, 0, 0);
                acc = __builtin_amdgcn_mfma_f32_16x16x32_f16(bf1, af[mt][1], acc, 0, 0, 0);
                const int w = mt * 16 + (lane & 15);
                if (w < len)
                    *(f16x4*)(dstBase + (((size_t)((c * 32 + w) * 32 + i)) << 10) + jl) = to_h4(acc);
            }
        }
    } else if (MODE == 0) {
        const f16* w2base = imgW2T + (((size_t)i * 2048) << 6);
        for (int t = 0; t < 16; t++) {
            const int jt_ = t * 4 + wv;              // 0..63
            const int jA = jt_ * 16 + (lane & 15);
            const int j = jt_ * 16 + (lane >> 4) * 4;
            const half8 bL0 = *(const half8*)(w2base + ((size_t)jA << 6) + ((lane >> 4) << 3));
            const half8 bL1 = *(const half8*)(w2base + ((size_t)jA << 6) + 32 + ((lane >> 4) << 3));
            #pragma unroll
            for (int mt = 0; mt < 2; mt++) {
                f32x4 aL = {0.f, 0.f, 0.f, 0.f};
                aL = __builtin_amdgcn_mfma_f32_16x16x32_f16(bL0, af[mt][0], aL, 0, 0, 0);
                aL = __builtin_amdgcn_mfma_f32_16x16x32_f16(bL1, af[mt][1], aL, 0, 0, 0);
                // stash lin pre in acc regs; compute gate next
                const half8 bG0 = *(const half8*)(w2base + ((size_t)(1024 + jA) << 6) + ((lane >> 4) << 3));
                const half8 bG1 = *(const half8*)(w2base + ((size_t)(1024 + jA) << 6) + 32 + ((lane >> 4) << 3));
                f32x4 aG = {0.f, 0.f, 0.f, 0.f};
                aG = __builtin_amdgcn_mfma_f32_16x16x32_f16(bG0, af[mt][0], aG, 0, 0, 0);
                aG = __builtin_amdgcn_mfma_f32_16x16x32_f16(bG1, af[mt][1], aG, 0, 0, 0);
                const int w = mt * 16 + (lane & 15);
                if (w < len) {
                    const size_t cw = (size_t)(c * 32 + w);
                    const f16x4 c1L = *(const f16x4*)(capW1 + cw * 2048 + j);
                    const f16x4 c1G = *(const f16x4*)(capW1 + cw * 2048 + 1024 + j);
                    const f32x4 bl = *(const f32x4*)(b_lin + j);
                    const f32x4 bg = *(const f32x4*)(b_gate + j);
                    const f16x4 cp = *(const f16x4*)(capH + cw * 1024 + j);
                    f16x4 o;
                    #pragma unroll
                    for (int r = 0; r < 4; r++) {
                        const float h = tanhf(aL[r] + (float)c1L[r] + bl[r]);
                        const float g = 1.f / (1.f + __expf(-(aG[r] + (float)c1G[r] + bg[r])));
                        o[r] = (f16)((float)cp[r] * g + h * (1.f - g));
                    }
                    *(f16x4*)(qOut + ((cw * 32 + i) << 10) + j) = o;
                }
            }
        }
    }

    // ---- cos reduce
    #pragma unroll
    for (int mask = 16; mask <= 32; mask <<= 1) {
        #pragma unroll
        for (int mt = 0; mt < 2; mt++) {
            w12L[mt] += __shfl_xor(w12L[mt], mask);
            w22L[mt] += __shfl_xor(w22L[mt], mask);
        }
    }
    if (lane < 16) {
        #pragma unroll
        for (int mt = 0; mt < 2; mt++) {
            sW12[wv][mt * 16 + lane] = w12L[mt];
            sW22[wv][mt * 16 + lane] = w22L[mt];
        }
    }
    __syncthreads();
    if (tid < 32) {
        const int w = tid;
        float part = 0.f;
        if (w < len) {
            const float a = sW12[0][w] + sW12[1][w] + sW12[2][w] + sW12[3][w];
            const float b = sW22[0][w] + sW22[1][w] + sW22[2][w] + sW22[3][w];
            part = a / fmaxf(sqrtf(w11Buf[c * 32 + w]) * sqrtf(b), EPS_);
        }
        for (int off = 16; off > 0; off >>= 1) part += __shfl_down(part, off);
        if (tid == 0) score[c * 32 + i] += part / (float)len;
    }
}

// q-half GEMM, operand-swapped (weights = A operand -> j contiguous per lane).
// BM=128 m, BN=256 (128 j x {lin,gate}), BK=32, dbuf 1-barrier, 8 waves.
// jt = bid&7 -> one j-tile per XCD (weights L2-resident, A re-read halved).
// mode0: capW1 = capH @ W1pair^T (M=1024). mode1: qnext = blend(...) (M=32768).
__global__ __launch_bounds__(512, 4) void qgemm_kernel(
    const f16* __restrict__ Aptr,
    const f16* __restrict__ wlinH, const f16* __restrict__ wgateH,
    const f16* __restrict__ preLin, const f16* __restrict__ preGate,
    const float* __restrict__ b_lin, const float* __restrict__ b_gate,
    f16* __restrict__ outp,
    const int* __restrict__ lens, const int mode)
{
    const int bid = blockIdx.x;
    const int jt = bid & 7;                 // 8 j-tiles of 128
    const int cm = bid >> 3;
    int len = 32;
    if (mode) { len = lens[cm >> 3]; if ((cm & 7) * 4 >= len) return; }
    const int m0 = cm * 128;

    __shared__ char sMem[49152];            // 2 bufs x (A 8K | B 16K)

    const int tid = threadIdx.x;
    const int lane = tid & 63;
    const int wv = tid >> 6;                // 0..7
    const int mq = wv >> 1;                 // m-quarter 0..3 (32 rows)
    const int nh = wv & 1;                  // n-half 0..1 (64 j x both mats)

    // B LDS row n (0..255): nh_=n>>7, r=n&127 -> jloc = nh_*64 + (r&63), mat = r>>6
    auto stage = [&](int b, int ks) {
        const int kk = ks * 32;
        char* base = sMem + b * 24576;
        {
            const int row = tid >> 2, kg = tid & 3;
            const f16* src = Aptr + (size_t)(m0 + row) * 1024 + kk + ((kg ^ ((row >> 1) & 3)) << 3);
            gload16(src, base + tid * 16);
        }
        #pragma unroll
        for (int p = 0; p < 2; p++) {
            const int u = tid + p * 512;
            const int n = u >> 2, kg = u & 3;
            const int r = n & 127;
            const int j = jt * 128 + (n >> 7) * 64 + (r & 63);
            const f16* wsrc = ((r < 64) ? wlinH : wgateH) + (size_t)j * 2048 + kk + ((kg ^ ((n >> 1) & 3)) << 3);
            gload16(wsrc, base + 8192 + u * 16);
        }
    };

    f32x4 acc[8][2];
    #pragma unroll
    for (int a = 0; a < 8; a++) { acc[a][0] = (f32x4){0,0,0,0}; acc[a][1] = (f32x4){0,0,0,0}; }

    stage(0, 0);
    __syncthreads();
    int cur = 0;
    for (int ks = 0; ks < 32; ks++) {
        if (ks < 31) stage(cur ^ 1, ks + 1);
        const char* cb = sMem + cur * 24576;
        half8 bq[2];
        #pragma unroll
        for (int mt = 0; mt < 2; mt++) {
            const int m = mq * 32 + mt * 16 + (lane & 15);
            bq[mt] = *(const half8*)(cb + m * 64 + ((((lane >> 4) ^ ((m >> 1) & 3))) << 4));
        }
        __builtin_amdgcn_s_setprio(1);
        #pragma unroll
        for (int half = 0; half < 2; half++) {     // 0: lin rows, 1: gate rows
            half8 aw[4];
            #pragma unroll
            for (int q = 0; q < 4; q++) {
                const int n = nh * 128 + half * 64 + q * 16 + (lane & 15);
                aw[q] = *(const half8*)(cb + 8192 + n * 64 + ((((lane >> 4) ^ ((n >> 1) & 3))) << 4));
            }
            #pragma unroll
            for (int q = 0; q < 4; q++)
                #pragma unroll
                for (int mt = 0; mt < 2; mt++)
                    acc[half * 4 + q][mt] = __builtin_amdgcn_mfma_f32_16x16x32_f16(aw[q], bq[mt], acc[half * 4 + q][mt], 0, 0, 0);
        }
        __builtin_amdgcn_s_setprio(0);
        __syncthreads();
        cur ^= 1;
    }

    // epilogue: lane holds fixed m, contiguous j-quads
    #pragma unroll
    for (int mt = 0; mt < 2; mt++) {
        const int gm = m0 + mq * 32 + mt * 16 + (lane & 15);
        bool active = true;
        if (mode) active = (((gm >> 5) & 31) < len);
        #pragma unroll
        for (int q = 0; q < 4; q++) {
            const int j = jt * 128 + nh * 64 + q * 16 + (lane >> 4) * 4;
            const f32x4 aL = acc[q][mt];
            const f32x4 aG = acc[q + 4][mt];
            if (mode == 0) {
                *(f16x4*)(outp + (size_t)gm * 2048 + j) = to_h4(aL);
                *(f16x4*)(outp + (size_t)gm * 2048 + 1024 + j) = to_h4(aG);
            } else if (active) {
                const size_t off = ((size_t)gm << 10) + j;
                const f16x4 pl = *(const f16x4*)(preLin + off);
                const f16x4 pg = *(const f16x4*)(preGate + off);
                const f16x4 qo = *(const f16x4*)(Aptr + off);
                const f32x4 bl = *(const f32x4*)(b_lin + j);
                const f32x4 bg = *(const f32x4*)(b_gate + j);
                f16x4 o;
                #pragma unroll
                for (int r = 0; r < 4; r++) {
                    const float h = tanhf(aL[r] + (float)pl[r] + bl[r]);
                    const float g = 1.f / (1.f + __expf(-(aG[r] + (float)pg[r] + bg[r])));
                    o[r] = (f16)((float)qo[r] * g + h * (1.f - g));
                }
                *(f16x4*)(outp + off) = o;
            }
        }
    }
}

__global__ __launch_bounds__(64) void loss_kernel(const float* __restrict__ score,
                                                  float* __restrict__ out)
{
    __shared__ float s[32][33];
    __shared__ float diag[32];
    const int tid = threadIdx.x;
    for (int idx = tid; idx < 1024; idx += 64) s[idx >> 5][idx & 31] = score[idx];
    __syncthreads();
    if (tid < 32) diag[tid] = s[tid][tid];
    __syncthreads();
    float total = 0.f;
    if (tid < 32) {
        float m1 = 0.f, m2 = 0.f;
        for (int k = 0; k < 32; k++) {
            if (k != tid) {
                m1 = fmaxf(m1, fmaxf(0.f, MARGIN_ + s[tid][k] - diag[tid]));
                m2 = fmaxf(m2, fmaxf(0.f, MARGIN_ + s[k][tid] - diag[tid]));
            }
        }
        total = m1 + m2;
    }
    for (int off = 32; off > 0; off >>= 1) total += __shfl_down(total, off);
    if (tid == 0) out[0] = total;
}

extern "C" void kernel_launch(void* const* d_in, const int* in_sizes, int n_in,
                              void* d_out, int out_size, void* d_ws, size_t ws_size,
                              hipStream_t stream) {
    const float* img    = (const float*)d_in[0];
    const float* cap    = (const float*)d_in[1];
    const int*   lens   = (const int*)d_in[2];
    const float* w_lin  = (const float*)d_in[3];
    const float* b_lin  = (const float*)d_in[4];
    const float* w_gate = (const float*)d_in[5];
    const float* b_gate = (const float*)d_in[6];
    float* out = (float*)d_out;

    char* ws = (char*)d_ws;
    f16* qA     = (f16*)(ws);                        // 64 MB
    f16* preLin = (f16*)(ws + 67108864);             // 64 MB (qB aliases here)
    f16* preGate= (f16*)(ws + 134217728);            // 64 MB
    f16* capH   = (f16*)(ws + 201326592);            // 2 MB
    f16* wlinH  = (f16*)(ws + 203423744);            // 4 MB
    f16* wgateH = (f16*)(ws + 207618048);            // 4 MB
    f16* imgH   = (f16*)(ws + 211812352);            // 4 MB region (1152 rows used)
    f16* imgTH  = (f16*)(ws + 216006656);            // 4 MB
    f16* imgW2T = (f16*)(ws + 220200960);            // 8 MB
    f16* capW1  = (f16*)(ws + 228589568);            // 4 MB
    float* w11Buf = (float*)(ws + 232783872);        // 4 KB
    float* score  = (float*)(ws + 232787968);        // 4 KB
    f16* qB = preLin;                                // alias (per-element RAW in-thread)

    hipMemsetAsync(score, 0, C_ * I_ * sizeof(float), stream);
    convert_kernel<<<dim3(6272), dim3(256), 0, stream>>>(cap, w_lin, w_gate, img, capH, wlinH, wgateH, imgH);
    transpose_kernel<<<dim3(1024), dim3(256), 0, stream>>>(img, imgTH);
    w11_kernel<<<dim3(1024), dim3(64), 0, stream>>>(cap, w11Buf);
    imgw2t_kernel<<<dim3(16, 32), dim3(256), 0, stream>>>(wlinH, wgateH, imgH, imgW2T);
    qgemm_kernel<<<dim3(64), dim3(512), 0, stream>>>(capH, wlinH, wgateH, (const f16*)0, (const f16*)0,
                                                     b_lin, b_gate, capW1, lens, 0);
    // iter 0: attn + fused qA blend
    attn_kernel<0><<<dim3(1024), dim3(256), 0, stream>>>(imgH, imgTH, imgW2T, capH, (const f16*)0,
                                                         capW1, b_lin, b_gate, w11Buf, lens,
                                                         preLin, preGate, qA, score);
    // iter 1: attn + pre stores
    attn_kernel<1><<<dim3(1024), dim3(256), 0, stream>>>(imgH, imgTH, imgW2T, capH, qA,
                                                         capW1, b_lin, b_gate, w11Buf, lens,
                                                         preLin, preGate, (f16*)0, score);
    qgemm_kernel<<<dim3(2048), dim3(512), 0, stream>>>(qA, wlinH, wgateH, preLin, preGate,
                                                       b_lin, b_gate, qB, lens, 1);
    // iter 2: score only
    attn_kernel<2><<<dim3(1024), dim3(256), 0, stream>>>(imgH, imgTH, imgW2T, capH, qB,
                                                         capW1, b_lin, b_gate, w11Buf, lens,
                                                         preLin, preGate, (f16*)0, score);

    loss_kernel<<<dim3(1), dim3(64), 0, stream>>>(score, out);
}

// Round 8
// 506.290 us; speedup vs baseline: 23.8879x; 1.1677x over previous
//
#include <hip/hip_runtime.h>
#include <hip/hip_fp16.h>

#define C_ 32
#define I_ 32
#define W_ 32
#define R_ 36
#define D_ 1024
#define EPS_ 1e-8f
#define LAMBDA_ 9.0f
#define MARGIN_ 0.2f

typedef _Float16 f16;
typedef f16 half8 __attribute__((ext_vector_type(8)));
typedef f16 f16x4 __attribute__((ext_vector_type(4)));
typedef float f32x4 __attribute__((ext_vector_type(4)));

__device__ __forceinline__ void gload16(const void* g, void* l) {
    __builtin_amdgcn_global_load_lds((const __attribute__((address_space(1))) void*)g,
                                     (__attribute__((address_space(3))) void*)l, 16, 0, 0);
}

__device__ __forceinline__ f16x4 to_h4(f32x4 v) {
    f16x4 o; o[0] = (f16)v[0]; o[1] = (f16)v[1]; o[2] = (f16)v[2]; o[3] = (f16)v[3];
    return o;
}

// fp32 -> fp16 of cap, w_lin, w_gate, img
__global__ __launch_bounds__(256) void convert_kernel(
    const float* __restrict__ cap, const float* __restrict__ wl, const float* __restrict__ wg,
    const float* __restrict__ img,
    f16* __restrict__ capH, f16* __restrict__ wlH, f16* __restrict__ wgH, f16* __restrict__ imgH)
{
    const int t = blockIdx.x * 256 + threadIdx.x;   // 1605632 total
    const float* src; f16* dst; int idx;
    if (t < 262144)        { src = cap; dst = capH; idx = t; }
    else if (t < 786432)   { src = wl;  dst = wlH;  idx = t - 262144; }
    else if (t < 1310720)  { src = wg;  dst = wgH;  idx = t - 786432; }
    else                   { src = img; dst = imgH; idx = t - 1310720; }
    float4 v = ((const float4*)src)[idx];
    f16x4 o; o[0] = (f16)v.x; o[1] = (f16)v.y; o[2] = (f16)v.z; o[3] = (f16)v.w;
    *(f16x4*)(dst + (size_t)idx * 4) = o;
}

// w11Buf[c*32+w] = sum_d cap^2 (exact fp32)
__global__ __launch_bounds__(64) void w11_kernel(const float* __restrict__ cap,
                                                 float* __restrict__ w11Buf)
{
    const int row = blockIdx.x;
    const float* p = cap + (size_t)row * 1024;
    float s = 0.f;
    for (int e = threadIdx.x; e < 1024; e += 64) { float v = p[e]; s += v * v; }
    for (int off = 32; off > 0; off >>= 1) s += __shfl_down(s, off);
    if (threadIdx.x == 0) w11Buf[row] = s;
}

// gramH[i][m][n] = sum_d img[i][m][d] img[i][n][d], (64x64 per i, zero pad >=36)
__global__ __launch_bounds__(256) void gram_kernel(const f16* __restrict__ imgH,
                                                   f16* __restrict__ gramH)
{
    __shared__ f16 sG[2][48 * 128];
    const int i = blockIdx.x;
    const int tid = threadIdx.x, lane = tid & 63, wv = tid >> 6;

    auto stage = [&](int b, int k0) {
        for (int g = wv; g < 12; g += 4) {
            const int row = g * 4 + (lane >> 4);
            gload16(imgH + (size_t)(i * 36 + row) * 1024 + k0 + (((lane & 15) ^ (row & 7)) << 3),
                    &sG[b][g * 512]);
        }
    };

    f32x4 acc[4];
    #pragma unroll
    for (int a = 0; a < 4; a++) acc[a] = (f32x4){0.f, 0.f, 0.f, 0.f};

    stage(0, 0);
    __syncthreads();
    int cur = 0;
    for (int kc = 0; kc < 8; kc++) {
        if (kc < 7) stage(cur ^ 1, (kc + 1) * 128);
        #pragma unroll
        for (int ks = 0; ks < 4; ks++) {
            const int arow = wv * 16 + (lane & 15);
            const half8 am = *(const half8*)&sG[cur][arow * 128 + ((((ks << 2) | (lane >> 4)) ^ (arow & 7)) << 3)];
            #pragma unroll
            for (int nt = 0; nt < 4; nt++) {
                const int brow = nt * 16 + (lane & 15);
                const half8 bn = *(const half8*)&sG[cur][brow * 128 + ((((ks << 2) | (lane >> 4)) ^ (brow & 7)) << 3)];
                acc[nt] = __builtin_amdgcn_mfma_f32_16x16x32_f16(am, bn, acc[nt], 0, 0, 0);
            }
        }
        __syncthreads();
        cur ^= 1;
    }
    #pragma unroll
    for (int nt = 0; nt < 4; nt++)
        #pragma unroll
        for (int r = 0; r < 4; r++) {
            const int m = wv * 16 + ((lane >> 4) << 2) + r;
            const int n = nt * 16 + (lane & 15);
            gramH[(size_t)i * 4096 + m * 64 + n] = (m < 36 && n < 36) ? (f16)acc[nt][r] : (f16)0.f;
        }
}

// imgW2T[i][j][r] = sum_d img[i][r][d] * Wpair2[j][d]
__global__ __launch_bounds__(256) void imgw2t_kernel(
    const f16* __restrict__ wlinH, const f16* __restrict__ wgateH,
    const f16* __restrict__ imgH, f16* __restrict__ imgW2T)
{
    const int jt = blockIdx.x;
    const int i  = blockIdx.y;
    __shared__ f16 sA[128 * 64];
    __shared__ f16 sB[64 * 64];
    const int tid = threadIdx.x, lane = tid & 63, wv = tid >> 6;
    const int wm = wv >> 1, wn = wv & 1;
    f32x4 acc[4][2];
    #pragma unroll
    for (int a = 0; a < 4; a++) { acc[a][0] = (f32x4){0,0,0,0}; acc[a][1] = (f32x4){0,0,0,0}; }

    for (int ks = 0; ks < 16; ks++) {
        const int kk = ks * 64;
        __syncthreads();
        #pragma unroll
        for (int p = 0; p < 4; p++) {
            const int u = tid + p * 256;
            const int row = u >> 3, ch = u & 7;
            const int jr = jt * 128 + row;
            const f16* src = ((jr < 1024) ? (wlinH + (size_t)jr * 2048)
                                          : (wgateH + (size_t)(jr - 1024) * 2048))
                             + 1024 + kk + ((ch ^ (row & 7)) << 3);
            gload16(src, (char*)sA + u * 16);
        }
        #pragma unroll
        for (int p = 0; p < 2; p++) {
            const int u = tid + p * 256;
            const int row = u >> 3, ch = u & 7;
            const f16* src = imgH + (size_t)(i * 36 + row) * 1024 + kk + ((ch ^ (row & 7)) << 3);
            gload16(src, (char*)sB + u * 16);
        }
        __syncthreads();
        #pragma unroll
        for (int ksub = 0; ksub < 2; ksub++) {
            const int kch = (ksub << 2) | (lane >> 4);
            half8 af[4], bf[2];
            #pragma unroll
            for (int tm = 0; tm < 4; tm++) {
                const int row = wm * 64 + tm * 16 + (lane & 15);
                af[tm] = *(const half8*)((const char*)sA + row * 128 + ((kch ^ (row & 7)) << 4));
            }
            #pragma unroll
            for (int tn = 0; tn < 2; tn++) {
                const int row = wn * 32 + tn * 16 + (lane & 15);
                bf[tn] = *(const half8*)((const char*)sB + row * 128 + ((kch ^ (row & 7)) << 4));
            }
            #pragma unroll
            for (int tm = 0; tm < 4; tm++)
                #pragma unroll
                for (int tn = 0; tn < 2; tn++)
                    acc[tm][tn] = __builtin_amdgcn_mfma_f32_16x16x32_f16(af[tm], bf[tn], acc[tm][tn], 0, 0, 0);
        }
    }
    #pragma unroll
    for (int tm = 0; tm < 4; tm++)
        #pragma unroll
        for (int tn = 0; tn < 2; tn++)
            #pragma unroll
            for (int r = 0; r < 4; r++) {
                const int j = jt * 128 + wm * 64 + tm * 16 + (lane >> 4) * 4 + r;
                const int rc = wn * 32 + tn * 16 + (lane & 15);
                imgW2T[((size_t)i * 2048 + j) * 64 + rc] = (rc < 36) ? (f16)acc[tm][tn][r] : (f16)0.f;
            }
}

__device__ __forceinline__ float smt_read(const f16* sSmT, int w, int r) {
    return (float)sSmT[w * 64 + ((((r >> 3) ^ (w & 7)) << 3) | (r & 7))];
}

// One WG per (c,i). Phase A MFMA -> softmax -> score via Gram/capImg -> pre/qOut.
// MODE 0: q=cap; save capImg0; fused qOut blend.  MODE 1: store pre.  MODE 2: score only.
template<int MODE>
__global__ __launch_bounds__(256, 3) void attn_kernel(
    const f16* __restrict__ imgH,
    const f16* __restrict__ gramH,      // (I,64,64)
    const f16* __restrict__ imgW2T,     // (I,2048,64)
    const f16* __restrict__ capH,
    const f16* __restrict__ qcur,       // (C,W,I,D)
    const f16* __restrict__ capW1,      // (C*W,2048)
    f16* __restrict__ capImg0,          // (C,I,W,64): write M0, read M1/M2
    const float* __restrict__ b_lin, const float* __restrict__ b_gate,
    const float* __restrict__ w11Buf,
    const int* __restrict__ lens,
    f16* __restrict__ preLin, f16* __restrict__ preGate,
    f16* __restrict__ qOut,
    float* __restrict__ score)
{
    __shared__ char sBig[40960];        // phase A: 2x10240 f16; phase B: tiles
    __shared__ f16 sSmT[2048];
    __shared__ float sAttn[36][33];
    __shared__ float sNrm[36];
    __shared__ float sW22[4][32];
    __shared__ float sW12f[32];

    const int bid = blockIdx.x;
    const int c  = bid >> 5;
    const int i  = ((bid & 7) << 2) | ((bid >> 3) & 3);   // XCD: same-i colocate
    const int len = lens[c];
    const int tid = threadIdx.x;
    const int lane = tid & 63;
    const int wv = tid >> 6;
    const int i36 = i * 36;
    const size_t ciw = ((size_t)(c * 32 + i)) << 5;       // (c*32+i)*32

    f16 (*sPA)[10240] = (f16(*)[10240])sBig;
    const f16* qB = (MODE == 0) ? (const f16*)0 : (qcur + ((size_t)c * 1024 + i) * 1024);

    f32x4 accA[2] = {{0.f,0.f,0.f,0.f},{0.f,0.f,0.f,0.f}};

    auto stageA = [&](int b, int k0) {
        for (int g = wv; g < 20; g += 4) {
            f16* dst; const f16* src;
            if (g < 12) {
                const int row = g * 4 + (lane >> 4);
                dst = &sPA[b][g * 512];
                src = imgH + (size_t)(i36 + row) * 1024 + k0 + (((lane & 15) ^ (row & 7)) << 3);
            } else {
                const int w = (g - 12) * 4 + (lane >> 4);
                dst = &sPA[b][6144 + (g - 12) * 512];
                src = ((MODE == 0) ? (capH + (size_t)(c * 32 + w) * 1024)
                                   : (qB + (size_t)w * (32 * 1024)))
                      + k0 + (((lane & 15) ^ (w & 7)) << 3);
            }
            gload16(src, dst);
        }
    };

    stageA(0, 0);
    __syncthreads();
    int cur = 0;
    for (int kc = 0; kc < 8; kc++) {
        if (kc < 7) stageA(cur ^ 1, (kc + 1) * 128);
        if (wv < 3) {
            #pragma unroll
            for (int ks = 0; ks < 4; ks++) {
                const int arow = wv * 16 + (lane & 15);
                const half8 af = *(const half8*)&sPA[cur][arow * 128 + ((((ks << 2) | (lane >> 4)) ^ (arow & 7)) << 3)];
                #pragma unroll
                for (int nt = 0; nt < 2; nt++) {
                    const int brow = nt * 16 + (lane & 15);
                    const half8 bf = *(const half8*)&sPA[cur][6144 + brow * 128 + ((((ks << 2) | (lane >> 4)) ^ (brow & 7)) << 3)];
                    accA[nt] = __builtin_amdgcn_mfma_f32_16x16x32_f16(af, bf, accA[nt], 0, 0, 0);
                }
            }
        }
        __syncthreads();
        cur ^= 1;
    }

    if (wv < 3) {
        #pragma unroll
        for (int nt = 0; nt < 2; nt++) {
            #pragma unroll
            for (int r = 0; r < 4; r++) {
                const int rr = wv * 16 + (lane >> 4) * 4 + r;
                if (rr < 36) {
                    float v = accA[nt][r];
                    sAttn[rr][nt * 16 + (lane & 15)] = (v >= 0.f) ? v : 0.1f * v;
                }
            }
        }
    }
    __syncthreads();

    if (tid < 36) {
        float s = 0.f;
        for (int w = 0; w < len; w++) { float v = sAttn[tid][w]; s += v * v; }
        sNrm[tid] = LAMBDA_ / (sqrtf(s) + EPS_);
    }
    __syncthreads();

    if (tid < 32) {
        if (tid < len) {
            float m = -1e30f;
            #pragma unroll
            for (int r = 0; r < 36; r++) m = fmaxf(m, sAttn[r][tid] * sNrm[r]);
            float sum = 0.f;
            #pragma unroll
            for (int r = 0; r < 36; r++) sum += __expf(sAttn[r][tid] * sNrm[r] - m);
            const float inv = 1.0f / sum;
            #pragma unroll
            for (int r = 0; r < 64; r++) {
                const int off = tid * 64 + ((((r >> 3) ^ (tid & 7)) << 3) | (r & 7));
                sSmT[off] = (r < 36) ? (f16)(__expf(sAttn[r][tid] * sNrm[r] - m) * inv) : (f16)0.f;
            }
        } else {
            #pragma unroll
            for (int r = 0; r < 64; r++) sSmT[tid * 64 + r] = (f16)0.f;
        }
    }
    __syncthreads();

    // MODE0: save raw attn (inv leaky-relu) as capImg0, coalesced half8
    if (MODE == 0) {
        const int w = tid >> 3, rg = tid & 7;
        half8 o;
        #pragma unroll
        for (int k = 0; k < 8; k++) {
            const int r = rg * 8 + k;
            float v = 0.f;
            if (r < 36) { v = sAttn[r][w]; v = (v >= 0.f) ? v : v * 10.f; }
            o[k] = (f16)v;
        }
        *(half8*)(capImg0 + ((ciw + w) << 6) + rg * 8) = o;
    }

    // sm fragments (B^T convention: row=w, k=r)
    half8 af[2][2];
    #pragma unroll
    for (int mt = 0; mt < 2; mt++)
        #pragma unroll
        for (int ks = 0; ks < 2; ks++) {
            const int row = mt * 16 + (lane & 15);
            af[mt][ks] = *(const half8*)&sSmT[row * 64 + ((((ks << 2) | (lane >> 4)) ^ (row & 7)) << 3)];
        }

    // w22 = sm^T G sm via one 64x32 MFMA slab per wave
    {
        const f16* gb = gramH + ((size_t)i << 12);
        const int arow = (wv << 4) + (lane & 15);
        const half8 gA0 = *(const half8*)(gb + arow * 64 + ((lane >> 4) << 3));
        const half8 gA1 = *(const half8*)(gb + arow * 64 + 32 + ((lane >> 4) << 3));
        float w22L[2] = {0.f, 0.f};
        #pragma unroll
        for (int mt = 0; mt < 2; mt++) {
            f32x4 t = {0.f, 0.f, 0.f, 0.f};
            t = __builtin_amdgcn_mfma_f32_16x16x32_f16(gA0, af[mt][0], t, 0, 0, 0);
            t = __builtin_amdgcn_mfma_f32_16x16x32_f16(gA1, af[mt][1], t, 0, 0, 0);
            const int w = mt * 16 + (lane & 15);
            const int rp = (wv << 4) + ((lane >> 4) << 2);
            #pragma unroll
            for (int r = 0; r < 4; r++)
                w22L[mt] += t[r] * smt_read(sSmT, w, rp + r);
        }
        #pragma unroll
        for (int mt = 0; mt < 2; mt++) {
            w22L[mt] += __shfl_xor(w22L[mt], 16);
            w22L[mt] += __shfl_xor(w22L[mt], 32);
        }
        if (lane < 16) {
            sW22[wv][lane] = w22L[0];
            sW22[wv][16 + lane] = w22L[1];
        }
    }

    // w12 = sum_r sm[w,r] * capImg[w,r]
    {
        const int w = tid >> 3, rg = tid & 7;
        float p = 0.f;
        if (MODE == 0) {
            #pragma unroll
            for (int k = 0; k < 8; k++) {
                const int r = rg * 8 + k;
                if (r < 36) {
                    float v = sAttn[r][w]; v = (v >= 0.f) ? v : v * 10.f;
                    p += v * smt_read(sSmT, w, r);
                }
            }
        } else {
            const half8 ci8 = *(const half8*)(capImg0 + ((ciw + w) << 6) + rg * 8);
            #pragma unroll
            for (int k = 0; k < 8; k++) {
                const int r = rg * 8 + k;
                if (r < 36) p += (float)ci8[k] * smt_read(sSmT, w, r);
            }
        }
        p += __shfl_xor(p, 1); p += __shfl_xor(p, 2); p += __shfl_xor(p, 4);
        if (rg == 0) sW12f[w] = p;
    }
    __syncthreads();

    if (tid < 32) {
        const int w = tid;
        float part = 0.f;
        if (w < len) {
            const float a = sW12f[w];
            const float b = sW22[0][w] + sW22[1][w] + sW22[2][w] + sW22[3][w];
            part = a / fmaxf(sqrtf(w11Buf[c * 32 + w]) * sqrtf(b), EPS_);
        }
        for (int off = 16; off > 0; off >>= 1) part += __shfl_down(part, off);
        if (tid == 0) score[c * 32 + i] += part / (float)len;
    }

    // ---- pre / qOut with LDS-transpose staged coalesced IO ----
    if (MODE == 1) {
        f16 (*tiles)[32][66] = (f16(*)[32][66])sBig;   // 2 x 4224B
        for (int t = 0; t < 32; t++) {
            const int jt_ = t * 4 + wv;
            const int jA = jt_ * 16 + (lane & 15);
            const f16* bb = imgW2T + ((size_t)i * 2048 + jA) * 64;
            const half8 bf0 = *(const half8*)(bb + ((lane >> 4) << 3));
            const half8 bf1 = *(const half8*)(bb + 32 + ((lane >> 4) << 3));
            #pragma unroll
            for (int mt = 0; mt < 2; mt++) {
                f32x4 acc = {0.f, 0.f, 0.f, 0.f};
                acc = __builtin_amdgcn_mfma_f32_16x16x32_f16(bf0, af[mt][0], acc, 0, 0, 0);
                acc = __builtin_amdgcn_mfma_f32_16x16x32_f16(bf1, af[mt][1], acc, 0, 0, 0);
                const int w = mt * 16 + (lane & 15);
                *(f16x4*)&tiles[t & 1][w][wv * 16 + ((lane >> 4) << 2)] = to_h4(acc);
            }
            __syncthreads();
            const int w = tid >> 3, jg = tid & 7;
            if (w < len) {
                f16* dst = (t < 16) ? preLin : preGate;
                const half8 v = *(const half8*)&tiles[t & 1][w][jg * 8];
                *(half8*)(dst + (((size_t)((c * 32 + w) * 32 + i)) << 10) + ((t * 64) & 1023) + jg * 8) = v;
            }
        }
    } else if (MODE == 0) {
        f16 (*tiles)[2][32][66] = (f16(*)[2][32][66])sBig;   // [dbuf][L/G]
        for (int t = 0; t < 16; t++) {
            const int jt_ = t * 4 + wv;
            const int jA = jt_ * 16 + (lane & 15);
            const f16* bbL = imgW2T + ((size_t)i * 2048 + jA) * 64;
            const f16* bbG = imgW2T + ((size_t)i * 2048 + 1024 + jA) * 64;
            const half8 bL0 = *(const half8*)(bbL + ((lane >> 4) << 3));
            const half8 bL1 = *(const half8*)(bbL + 32 + ((lane >> 4) << 3));
            const half8 bG0 = *(const half8*)(bbG + ((lane >> 4) << 3));
            const half8 bG1 = *(const half8*)(bbG + 32 + ((lane >> 4) << 3));
            #pragma unroll
            for (int mt = 0; mt < 2; mt++) {
                f32x4 aL = {0.f, 0.f, 0.f, 0.f}, aG = {0.f, 0.f, 0.f, 0.f};
                aL = __builtin_amdgcn_mfma_f32_16x16x32_f16(bL0, af[mt][0], aL, 0, 0, 0);
                aL = __builtin_amdgcn_mfma_f32_16x16x32_f16(bL1, af[mt][1], aL, 0, 0, 0);
                aG = __builtin_amdgcn_mfma_f32_16x16x32_f16(bG0, af[mt][0], aG, 0, 0, 0);
                aG = __builtin_amdgcn_mfma_f32_16x16x32_f16(bG1, af[mt][1], aG, 0, 0, 0);
                const int w = mt * 16 + (lane & 15);
                const int x = wv * 16 + ((lane >> 4) << 2);
                *(f16x4*)&tiles[t & 1][0][w][x] = to_h4(aL);
                *(f16x4*)&tiles[t & 1][1][w][x] = to_h4(aG);
            }
            __syncthreads();
            const int w = tid >> 3, jg = tid & 7;
            if (w < len) {
                const int j = t * 64 + jg * 8;
                const size_t cw = (size_t)(c * 32 + w);
                const half8 l8 = *(const half8*)&tiles[t & 1][0][w][jg * 8];
                const half8 g8 = *(const half8*)&tiles[t & 1][1][w][jg * 8];
                const half8 c1L = *(const half8*)(capW1 + cw * 2048 + j);
                const half8 c1G = *(const half8*)(capW1 + cw * 2048 + 1024 + j);
                const half8 cp  = *(const half8*)(capH + cw * 1024 + j);
                half8 o;
                #pragma unroll
                for (int k = 0; k < 8; k++) {
                    const float h = tanhf((float)l8[k] + (float)c1L[k] + b_lin[j + k]);
                    const float g = 1.f / (1.f + __expf(-((float)g8[k] + (float)c1G[k] + b_gate[j + k])));
                    o[k] = (f16)((float)cp[k] * g + h * (1.f - g));
                }
                *(half8*)(qOut + ((cw * 32 + i) << 10) + j) = o;
            }
        }
    }
}

// q-half GEMM: A rows = A-operand, weights = B-operand -> col(lane&15)=j (coalesced IO).
__global__ __launch_bounds__(512, 4) void qgemm_kernel(
    const f16* __restrict__ Aptr,
    const f16* __restrict__ wlinH, const f16* __restrict__ wgateH,
    const f16* __restrict__ preLin, const f16* __restrict__ preGate,
    const float* __restrict__ b_lin, const float* __restrict__ b_gate,
    f16* __restrict__ outp,
    const int* __restrict__ lens, const int mode)
{
    const int bid = blockIdx.x;
    const int jt = bid & 7;
    const int cm = bid >> 3;
    int len = 32;
    if (mode) { len = lens[cm >> 3]; if ((cm & 7) * 4 >= len) return; }
    const int m0 = cm * 128;

    __shared__ char sMem[49152];

    const int tid = threadIdx.x;
    const int lane = tid & 63;
    const int wv = tid >> 6;
    const int mq = wv >> 1;
    const int nh = wv & 1;

    auto stage = [&](int b, int ks) {
        const int kk = ks * 32;
        char* base = sMem + b * 24576;
        {
            const int row = tid >> 2, kg = tid & 3;
            const f16* src = Aptr + (size_t)(m0 + row) * 1024 + kk + ((kg ^ ((row >> 1) & 3)) << 3);
            gload16(src, base + tid * 16);
        }
        #pragma unroll
        for (int p = 0; p < 2; p++) {
            const int u = tid + p * 512;
            const int n = u >> 2, kg = u & 3;
            const int r = n & 127;
            const int j = jt * 128 + (n >> 7) * 64 + (r & 63);
            const f16* wsrc = ((r < 64) ? wlinH : wgateH) + (size_t)j * 2048 + kk + ((kg ^ ((n >> 1) & 3)) << 3);
            gload16(wsrc, base + 8192 + u * 16);
        }
    };

    f32x4 acc[8][2];
    #pragma unroll
    for (int a = 0; a < 8; a++) { acc[a][0] = (f32x4){0,0,0,0}; acc[a][1] = (f32x4){0,0,0,0}; }

    stage(0, 0);
    __syncthreads();
    int cur = 0;
    for (int ks = 0; ks < 32; ks++) {
        if (ks < 31) stage(cur ^ 1, ks + 1);
        const char* cb = sMem + cur * 24576;
        half8 bq[2];
        #pragma unroll
        for (int mt = 0; mt < 2; mt++) {
            const int m = mq * 32 + mt * 16 + (lane & 15);
            bq[mt] = *(const half8*)(cb + m * 64 + ((((lane >> 4) ^ ((m >> 1) & 3))) << 4));
        }
        __builtin_amdgcn_s_setprio(1);
        #pragma unroll
        for (int half = 0; half < 2; half++) {
            half8 aw[4];
            #pragma unroll
            for (int q = 0; q < 4; q++) {
                const int n = nh * 128 + half * 64 + q * 16 + (lane & 15);
                aw[q] = *(const half8*)(cb + 8192 + n * 64 + ((((lane >> 4) ^ ((n >> 1) & 3))) << 4));
            }
            #pragma unroll
            for (int q = 0; q < 4; q++)
                #pragma unroll
                for (int mt = 0; mt < 2; mt++)
                    acc[half * 4 + q][mt] = __builtin_amdgcn_mfma_f32_16x16x32_f16(bq[mt], aw[q], acc[half * 4 + q][mt], 0, 0, 0);
        }
        __builtin_amdgcn_s_setprio(0);
        __syncthreads();
        cur ^= 1;
    }

    // epilogue: col = j (16 consecutive j per 16-lane group), rows m in reg quad
    #pragma unroll
    for (int q = 0; q < 4; q++) {
        const int j = jt * 128 + nh * 64 + q * 16 + (lane & 15);
        const float blv = b_lin[j], bgv = b_gate[j];
        #pragma unroll
        for (int mt = 0; mt < 2; mt++) {
            #pragma unroll
            for (int r = 0; r < 4; r++) {
                const int gm = m0 + mq * 32 + mt * 16 + ((lane >> 4) << 2) + r;
                const float aL = acc[q][mt][r];
                const float aG = acc[q + 4][mt][r];
                if (mode == 0) {
                    outp[(size_t)gm * 2048 + j] = (f16)aL;
                    outp[(size_t)gm * 2048 + 1024 + j] = (f16)aG;
                } else if (((gm >> 5) & 31) < len) {
                    const size_t off = ((size_t)gm << 10) + j;
                    const float h = tanhf(aL + (float)preLin[off] + blv);
                    const float g = 1.f / (1.f + __expf(-(aG + (float)preGate[off] + bgv)));
                    outp[off] = (f16)((float)Aptr[off] * g + h * (1.f - g));
                }
            }
        }
    }
}

__global__ __launch_bounds__(64) void loss_kernel(const float* __restrict__ score,
                                                  float* __restrict__ out)
{
    __shared__ float s[32][33];
    __shared__ float diag[32];
    const int tid = threadIdx.x;
    for (int idx = tid; idx < 1024; idx += 64) s[idx >> 5][idx & 31] = score[idx];
    __syncthreads();
    if (tid < 32) diag[tid] = s[tid][tid];
    __syncthreads();
    float total = 0.f;
    if (tid < 32) {
        float m1 = 0.f, m2 = 0.f;
        for (int k = 0; k < 32; k++) {
            if (k != tid) {
                m1 = fmaxf(m1, fmaxf(0.f, MARGIN_ + s[tid][k] - diag[tid]));
                m2 = fmaxf(m2, fmaxf(0.f, MARGIN_ + s[k][tid] - diag[tid]));
            }
        }
        total = m1 + m2;
    }
    for (int off = 32; off > 0; off >>= 1) total += __shfl_down(total, off);
    if (tid == 0) out[0] = total;
}

extern "C" void kernel_launch(void* const* d_in, const int* in_sizes, int n_in,
                              void* d_out, int out_size, void* d_ws, size_t ws_size,
                              hipStream_t stream) {
    const float* img    = (const float*)d_in[0];
    const float* cap    = (const float*)d_in[1];
    const int*   lens   = (const int*)d_in[2];
    const float* w_lin  = (const float*)d_in[3];
    const float* b_lin  = (const float*)d_in[4];
    const float* w_gate = (const float*)d_in[5];
    const float* b_gate = (const float*)d_in[6];
    float* out = (float*)d_out;

    char* ws = (char*)d_ws;
    f16* qA      = (f16*)(ws);                       // 64 MB
    f16* preLin  = (f16*)(ws + 67108864);            // 64 MB (qB aliases)
    f16* preGate = (f16*)(ws + 134217728);           // 64 MB
    f16* capH    = (f16*)(ws + 201326592);           // 2 MB
    f16* wlinH   = (f16*)(ws + 203423744);           // 4 MB
    f16* wgateH  = (f16*)(ws + 207618048);           // 4 MB
    f16* imgH    = (f16*)(ws + 211812352);           // ~2.4 MB used
    f16* gramH   = (f16*)(ws + 214958080);           // 256 KB
    f16* capImg0 = (f16*)(ws + 216006656);           // 4 MB
    f16* imgW2T  = (f16*)(ws + 220200960);           // 8 MB
    f16* capW1   = (f16*)(ws + 228589568);           // 4 MB
    float* w11Buf = (float*)(ws + 232783872);
    float* score  = (float*)(ws + 232787968);
    f16* qB = preLin;                                // alias

    hipMemsetAsync(score, 0, C_ * I_ * sizeof(float), stream);
    convert_kernel<<<dim3(6272), dim3(256), 0, stream>>>(cap, w_lin, w_gate, img, capH, wlinH, wgateH, imgH);
    w11_kernel<<<dim3(1024), dim3(64), 0, stream>>>(cap, w11Buf);
    gram_kernel<<<dim3(32), dim3(256), 0, stream>>>(imgH, gramH);
    imgw2t_kernel<<<dim3(16, 32), dim3(256), 0, stream>>>(wlinH, wgateH, imgH, imgW2T);
    qgemm_kernel<<<dim3(64), dim3(512), 0, stream>>>(capH, wlinH, wgateH, (const f16*)0, (const f16*)0,
                                                     b_lin, b_gate, capW1, lens, 0);
    // iter 0
    attn_kernel<0><<<dim3(1024), dim3(256), 0, stream>>>(imgH, gramH, imgW2T, capH, (const f16*)0,
                                                         capW1, capImg0, b_lin, b_gate, w11Buf, lens,
                                                         preLin, preGate, qA, score);
    // iter 1
    attn_kernel<1><<<dim3(1024), dim3(256), 0, stream>>>(imgH, gramH, imgW2T, capH, qA,
                                                         capW1, capImg0, b_lin, b_gate, w11Buf, lens,
                                                         preLin, preGate, (f16*)0, score);
    qgemm_kernel<<<dim3(2048), dim3(512), 0, stream>>>(qA, wlinH, wgateH, preLin, preGate,
                                                       b_lin, b_gate, qB, lens, 1);
    // iter 2
    attn_kernel<2><<<dim3(1024), dim3(256), 0, stream>>>(imgH, gramH, imgW2T, capH, qB,
                                                         capW1, capImg0, b_lin, b_gate, w11Buf, lens,
                                                         preLin, preGate, (f16*)0, score);

    loss_kernel<<<dim3(1), dim3(64), 0, stream>>>(score, out);
}